// Round 5
// baseline (451.622 us; speedup 1.0000x reference)
//
#include <hip/hip_runtime.h>
#include <cstdint>
#include <cstddef>

typedef __bf16 bf16;
typedef __bf16 v8bf __attribute__((ext_vector_type(8)));
typedef float  v4f  __attribute__((ext_vector_type(4)));

#define D_MODEL 1024
#define FF_DIM  4096
#define SEQ     2048
#define NTOK    4096   // B*S
#define NH      16
#define HDIM    64

#define GLOAD_LDS16(g, l) \
    __builtin_amdgcn_global_load_lds((const __attribute__((address_space(1))) void*)(g), \
                                     (__attribute__((address_space(3))) void*)(l), 16, 0, 0)

// ---------------- prep: all weight converts + acc zeroing, one dispatch ------
// ranges in float4 units: Wqkv 786432 | Wo 262144 | W1 1048576 | W2 1048576 |
// acc zero 1064960  (total 4210688 threads = 16448 blocks)
__global__ __launch_bounds__(256) void prep_kernel(
    const float* __restrict__ Wqkv, const float* __restrict__ Wo,
    const float* __restrict__ W1, const float* __restrict__ W2,
    bf16* __restrict__ Wqkv_b, bf16* __restrict__ Wo_b,
    bf16* __restrict__ W1_b, bf16* __restrict__ W2_b,
    float* __restrict__ acc) {
    int u = blockIdx.x * 256 + threadIdx.x;
    const float* src; bf16* dst; int idx;
    if (u < 786432)       { src = Wqkv; dst = Wqkv_b; idx = u * 4; }
    else if (u < 1048576) { src = Wo;   dst = Wo_b;   idx = (u - 786432) * 4; }
    else if (u < 2097152) { src = W1;   dst = W1_b;   idx = (u - 1048576) * 4; }
    else if (u < 3145728) { src = W2;   dst = W2_b;   idx = (u - 2097152) * 4; }
    else {
        *(float4*)(acc + (size_t)(u - 3145728) * 4) = (float4){0.f, 0.f, 0.f, 0.f};
        return;
    }
    float4 v = *(const float4*)(src + idx);
    dst[idx + 0] = (bf16)v.x;
    dst[idx + 1] = (bf16)v.y;
    dst[idx + 2] = (bf16)v.z;
    dst[idx + 3] = (bf16)v.w;
}

// ---------------- init: out = a + bias (bias broadcast over D_MODEL) --------
__global__ __launch_bounds__(256) void init_bias_kernel(
    const float* __restrict__ a, const float* __restrict__ bias,
    float* __restrict__ out) {
    int i = (blockIdx.x * 256 + threadIdx.x) * 4;
    int col = i & (D_MODEL - 1);
    float4 av = *(const float4*)(a + i);
    float4 bv = *(const float4*)(bias + col);
    float4 r;
    r.x = av.x + bv.x; r.y = av.y + bv.y; r.z = av.z + bv.z; r.w = av.w + bv.w;
    *(float4*)(out + i) = r;
}

// ---------------- LayerNorm (unbiased std, eps on std) ----------------
__global__ __launch_bounds__(256) void layernorm_kernel(
    const float* __restrict__ x, const float* __restrict__ scale,
    const float* __restrict__ shift, bf16* __restrict__ out) {
    int row = blockIdx.x;
    int t = threadIdx.x;
    const float* xr = x + (size_t)row * D_MODEL;
    float4 v = *(const float4*)(xr + t * 4);
    float s  = v.x + v.y + v.z + v.w;
    float sq = v.x * v.x + v.y * v.y + v.z * v.z + v.w * v.w;
    #pragma unroll
    for (int o = 1; o < 64; o <<= 1) {
        s  += __shfl_xor(s, o);
        sq += __shfl_xor(sq, o);
    }
    __shared__ float ws[8];
    int wv = t >> 6;
    if ((t & 63) == 0) { ws[wv * 2] = s; ws[wv * 2 + 1] = sq; }
    __syncthreads();
    s  = ws[0] + ws[2] + ws[4] + ws[6];
    sq = ws[1] + ws[3] + ws[5] + ws[7];
    float mean = s * (1.0f / D_MODEL);
    float var  = (sq - (float)D_MODEL * mean * mean) * (1.0f / (D_MODEL - 1));
    var = fmaxf(var, 0.0f);
    float inv = 1.0f / (sqrtf(var) + 1e-5f);
    #pragma unroll
    for (int j = 0; j < 4; ++j) {
        int c = t * 4 + j;
        float xv = (&v.x)[j];
        out[(size_t)row * D_MODEL + c] = (bf16)(shift[c] + scale[c] * (xv - mean) * inv);
    }
}

// ---------------- MFMA GEMM:  C[M,N] = A[M,K] * Bw[N,K]^T  ----------------
// global_load_lds width-16 staging, XOR-swizzled LDS chunks.
// EPI 0: QKV merged: cols<2048 -> q (x1/8) / k [BH,S,HD]; cols>=2048 -> V^T
//        [BH,HD,S] via block-uniform operand-swapped MFMA (transposed C).
// EPI 2: ob0 = gelu(C + bias)             (bf16 out, row stride N)
// EPI 5: atomicAdd(outf[row*N+col], C)    (split-K, dst pre-init w/ resid+bias)
template <int EPI>
__global__ __launch_bounds__(256) void gemm_nt(
    const bf16* __restrict__ A, const bf16* __restrict__ Bw,
    const float* __restrict__ bias, float* __restrict__ outf,
    bf16* __restrict__ ob0, bf16* __restrict__ ob1, bf16* __restrict__ ob2,
    int M, int N, int K, int klen) {
    __shared__ __align__(16) bf16 As[128 * 32];
    __shared__ __align__(16) bf16 Bs[128 * 32];
    int m0 = blockIdx.y * 128, n0 = blockIdx.x * 128;
    int kstart = blockIdx.z * klen;
    int t = threadIdx.x;
    int lane = t & 63, wave = t >> 6;
    int wm = wave >> 1, wn = wave & 1;
    int quad = lane >> 4, l16 = lane & 15;
    const bool trans = (EPI == 0) && (n0 >= 2048);

    int srow = lane >> 2;
    int schunk = (lane & 3) ^ (srow & 3);     // XOR swizzle
    const bf16* agp = A  + (size_t)(m0 + wave * 16 + srow) * K + kstart + schunk * 8;
    const bf16* bgp = Bw + (size_t)(n0 + wave * 16 + srow) * K + kstart + schunk * 8;
    bf16* aldst0 = &As[wave * 512];
    bf16* aldst1 = &As[(wave + 4) * 512];
    bf16* bldst0 = &Bs[wave * 512];
    bf16* bldst1 = &Bs[(wave + 4) * 512];

    v4f acc[4][4];
    #pragma unroll
    for (int i = 0; i < 4; ++i)
        #pragma unroll
        for (int j = 0; j < 4; ++j)
            acc[i][j] = (v4f){0.f, 0.f, 0.f, 0.f};

    int sw = l16 & 3;
    for (int kk = 0; kk < klen; kk += 32) {
        __syncthreads();
        GLOAD_LDS16(agp + kk,                  aldst0);
        GLOAD_LDS16(agp + (size_t)64 * K + kk, aldst1);
        GLOAD_LDS16(bgp + kk,                  bldst0);
        GLOAD_LDS16(bgp + (size_t)64 * K + kk, bldst1);
        __syncthreads();
        v8bf af[4], bfr[4];
        #pragma unroll
        for (int i = 0; i < 4; ++i)
            af[i] = *(const v8bf*)(&As[(wm * 64 + i * 16 + l16) * 32 + (quad ^ sw) * 8]);
        #pragma unroll
        for (int j = 0; j < 4; ++j)
            bfr[j] = *(const v8bf*)(&Bs[(wn * 64 + j * 16 + l16) * 32 + (quad ^ sw) * 8]);
        if (!trans) {
            #pragma unroll
            for (int i = 0; i < 4; ++i)
                #pragma unroll
                for (int j = 0; j < 4; ++j)
                    acc[i][j] = __builtin_amdgcn_mfma_f32_16x16x32_bf16(af[i], bfr[j], acc[i][j], 0, 0, 0);
        } else {
            #pragma unroll
            for (int i = 0; i < 4; ++i)
                #pragma unroll
                for (int j = 0; j < 4; ++j)
                    acc[i][j] = __builtin_amdgcn_mfma_f32_16x16x32_bf16(bfr[j], af[i], acc[i][j], 0, 0, 0);
        }
    }

    #pragma unroll
    for (int i = 0; i < 4; ++i) {
        #pragma unroll
        for (int j = 0; j < 4; ++j) {
            #pragma unroll
            for (int r = 0; r < 4; ++r) {
                float v = acc[i][j][r];
                if (EPI == 0) {
                    if (trans) {
                        int wrow = n0 + wn * 64 + j * 16 + quad * 4 + r;
                        int tok  = m0 + wm * 64 + i * 16 + l16;
                        int rr = wrow - 2048;
                        int h = rr >> 6, d = rr & 63;
                        int b = tok >> 11, sI = tok & 2047;
                        ob2[(((size_t)(b * NH + h)) * HDIM + d) * SEQ + sI] = (bf16)v;
                    } else {
                        int row = m0 + wm * 64 + i * 16 + quad * 4 + r;
                        int col = n0 + wn * 64 + j * 16 + l16;
                        int which = col >> 10, rr = col & 1023;
                        int h = rr >> 6, d = rr & 63;
                        int b = row >> 11, sI = row & 2047;
                        if (which == 0) {
                            ob0[(((size_t)(b * NH + h)) * SEQ + sI) * HDIM + d] = (bf16)(v * 0.125f);
                        } else {
                            ob1[(((size_t)(b * NH + h)) * SEQ + sI) * HDIM + d] = (bf16)v;
                        }
                    }
                } else {
                    int row = m0 + wm * 64 + i * 16 + quad * 4 + r;
                    int col = n0 + wn * 64 + j * 16 + l16;
                    if (EPI == 2) {
                        float u = v + bias[col];
                        float y = 1.5957691216057308f * (u + 0.044715f * u * u * u);
                        float g = u * __builtin_amdgcn_rcpf(1.0f + __expf(-y));
                        ob0[(size_t)row * N + col] = (bf16)g;
                    } else {   // EPI 5
                        atomicAdd(&outf[(size_t)row * N + col], v);
                    }
                }
            }
        }
    }
}

// ---------------- Flash attention (causal), split-KV with additive partials --
__global__ __launch_bounds__(256) void attn_kernel(
    const bf16* __restrict__ qb, const bf16* __restrict__ kb,
    const bf16* __restrict__ vt, float* __restrict__ accO,
    float* __restrict__ accL) {
    int u = blockIdx.x;
    int bh = u / 80;
    int r80 = u - bh * 80;
    int qt, st;
    if (r80 < 8)       { qt = r80;                 st = 0; }
    else if (r80 < 24) { qt = 8  + ((r80 - 8) >> 1);  st = (r80 - 8) & 1; }
    else if (r80 < 48) { qt = 16 + (r80 - 24) / 3;    st = (r80 - 24) % 3; }
    else               { qt = 24 + ((r80 - 48) >> 2); st = (r80 - 48) & 3; }
    int qbase = qt * 64;
    int kv0 = st * 512;
    int kv1 = min(qbase + 64, kv0 + 512);

    int t = threadIdx.x;
    int wave = t >> 6, lane = t & 63;
    int quad = lane >> 4, l16 = lane & 15;
    int qwb = qbase + wave * 16;

    const bf16* Qh  = qb + (size_t)bh * SEQ * HDIM;
    const bf16* Kh  = kb + (size_t)bh * SEQ * HDIM;
    const bf16* Vth = vt + (size_t)bh * HDIM * SEQ;

    __shared__ __align__(16) bf16 Ks[64 * 64];
    __shared__ __align__(16) bf16 Vs[64 * 64];
    __shared__ __align__(16) bf16 Ps[4][16 * 80];
    bf16* Pw = &Ps[wave][0];

    int u0 = t, u1 = t + 256;
    int key0 = u0 >> 3, c0 = (u0 & 7) ^ (key0 & 7);
    int key1 = u1 >> 3, c1 = (u1 & 7) ^ (key1 & 7);
    bf16* kdst0 = &Ks[wave * 512];
    bf16* kdst1 = &Ks[2048 + wave * 512];
    bf16* vdst0 = &Vs[wave * 512];
    bf16* vdst1 = &Vs[2048 + wave * 512];
    const bf16* Ksrc0 = Kh + (size_t)key0 * HDIM + c0 * 8;
    const bf16* Ksrc1 = Kh + (size_t)key1 * HDIM + c1 * 8;
    const bf16* Vsrc0 = Vth + (size_t)key0 * SEQ + c0 * 8;
    const bf16* Vsrc1 = Vth + (size_t)key1 * SEQ + c1 * 8;

    v8bf qf0 = *(const v8bf*)(Qh + (size_t)(qwb + l16) * HDIM + quad * 8);
    v8bf qf1 = *(const v8bf*)(Qh + (size_t)(qwb + l16) * HDIM + 32 + quad * 8);

    v4f o[4];
    #pragma unroll
    for (int dc = 0; dc < 4; ++dc) o[dc] = (v4f){0.f, 0.f, 0.f, 0.f};
    float lsum = 0.f;

    for (int kv = kv0; kv < kv1; kv += 64) {
        __syncthreads();
        GLOAD_LDS16(Ksrc0 + (size_t)kv * HDIM, kdst0);
        GLOAD_LDS16(Ksrc1 + (size_t)kv * HDIM, kdst1);
        GLOAD_LDS16(Vsrc0 + kv, vdst0);
        GLOAD_LDS16(Vsrc1 + kv, vdst1);
        __syncthreads();

        bool domask = (kv + 63 > qwb);
        #pragma unroll
        for (int j = 0; j < 4; ++j) {
            int key = j * 16 + l16;
            v8bf ka = *(const v8bf*)(&Ks[(key * 8 + (quad ^ (key & 7))) * 8]);
            v8bf kc = *(const v8bf*)(&Ks[(key * 8 + ((quad + 4) ^ (key & 7))) * 8]);
            v4f s = (v4f){-20.f, -20.f, -20.f, -20.f};
            s = __builtin_amdgcn_mfma_f32_16x16x32_bf16(ka, qf0, s, 0, 0, 0);
            s = __builtin_amdgcn_mfma_f32_16x16x32_bf16(kc, qf1, s, 0, 0, 0);
            int keyb = kv + j * 16 + quad * 4;
            union { bf16 h[4]; uint2 u; } pk;
            #pragma unroll
            for (int r = 0; r < 4; ++r) {
                float pv = __expf(s[r]);
                if (domask) pv = (keyb + r <= qwb + l16) ? pv : 0.f;
                lsum += pv;
                pk.h[r] = (bf16)pv;
            }
            *(uint2*)(&Pw[l16 * 80 + j * 16 + quad * 4]) = pk.u;
        }

        v8bf pf0 = *(const v8bf*)(&Pw[l16 * 80 + quad * 8]);
        v8bf pf1 = *(const v8bf*)(&Pw[l16 * 80 + 32 + quad * 8]);
        #pragma unroll
        for (int dc = 0; dc < 4; ++dc) {
            int dim = dc * 16 + l16;
            v8bf va = *(const v8bf*)(&Vs[(dim * 8 + (quad ^ (dim & 7))) * 8]);
            v8bf vc = *(const v8bf*)(&Vs[(dim * 8 + ((quad + 4) ^ (dim & 7))) * 8]);
            o[dc] = __builtin_amdgcn_mfma_f32_16x16x32_bf16(pf0, va, o[dc], 0, 0, 0);
            o[dc] = __builtin_amdgcn_mfma_f32_16x16x32_bf16(pf1, vc, o[dc], 0, 0, 0);
        }
    }

    lsum += __shfl_xor(lsum, 16);
    lsum += __shfl_xor(lsum, 32);
    if (quad == 0) atomicAdd(&accL[(size_t)bh * SEQ + qwb + l16], lsum);

    #pragma unroll
    for (int r = 0; r < 4; ++r) {
        int row = qwb + quad * 4 + r;
        #pragma unroll
        for (int dc = 0; dc < 4; ++dc) {
            atomicAdd(&accO[((size_t)bh * SEQ + row) * HDIM + dc * 16 + l16], o[dc][r]);
        }
    }
}

// ---------------- attention finalize: ob = accO / accL ----------------
__global__ __launch_bounds__(256) void attn_finalize(
    const float* __restrict__ accO, const float* __restrict__ accL,
    bf16* __restrict__ ob) {
    int i = (blockIdx.x * 256 + threadIdx.x) * 4;   // over 32*2048*64
    int bh = i >> 17;
    int rem = i & 131071;
    int s = rem >> 6, d0 = rem & 63;
    float inv = 1.0f / accL[(size_t)bh * SEQ + s];
    float4 o = *(const float4*)(accO + i);
    int b = bh >> 4, h = bh & 15;
    bf16* dst = ob + ((size_t)(b * SEQ + s)) * D_MODEL + h * HDIM + d0;
    dst[0] = (bf16)(o.x * inv);
    dst[1] = (bf16)(o.y * inv);
    dst[2] = (bf16)(o.z * inv);
    dst[3] = (bf16)(o.w * inv);
}

// ---------------- launch ----------------
extern "C" void kernel_launch(void* const* d_in, const int* in_sizes, int n_in,
                              void* d_out, int out_size, void* d_ws, size_t ws_size,
                              hipStream_t stream) {
    const float* x      = (const float*)d_in[0];
    const float* scale1 = (const float*)d_in[1];
    const float* shift1 = (const float*)d_in[2];
    const float* Wqkv   = (const float*)d_in[3];
    const float* Wo_w   = (const float*)d_in[4];
    const float* Wo_b   = (const float*)d_in[5];
    const float* scale2 = (const float*)d_in[6];
    const float* shift2 = (const float*)d_in[7];
    const float* W1     = (const float*)d_in[8];
    const float* b1     = (const float*)d_in[9];
    const float* W2     = (const float*)d_in[10];
    const float* b2     = (const float*)d_in[11];
    float* out = (float*)d_out;

    char* ws = (char*)d_ws;
    size_t off = 0;
    auto alloc = [&](size_t bytes) -> char* {
        char* p = ws + off;
        off += (bytes + 255) & ~(size_t)255;
        return p;
    };
    bf16* Wqkv_b = (bf16*)alloc((size_t)3 * D_MODEL * D_MODEL * 2);
    bf16* Wo_bf  = (bf16*)alloc((size_t)D_MODEL * D_MODEL * 2);
    bf16* W1_b   = (bf16*)alloc((size_t)FF_DIM * D_MODEL * 2);
    bf16* W2_b   = (bf16*)alloc((size_t)D_MODEL * FF_DIM * 2);
    bf16* bufA   = (bf16*)alloc((size_t)NTOK * D_MODEL * 2);   // h1 / attn out
    bf16* qb     = (bf16*)alloc((size_t)NTOK * D_MODEL * 2);   // q / h2
    bf16* kb     = (bf16*)alloc((size_t)NTOK * D_MODEL * 2);
    bf16* vtb    = (bf16*)alloc((size_t)NTOK * D_MODEL * 2);   // V transposed
    float* x1    = (float*)alloc((size_t)NTOK * D_MODEL * 4);
    bf16* mbuf   = (bf16*)alloc((size_t)NTOK * FF_DIM * 2);
    // attention accumulators alias mbuf (dead until W1)
    float* accO = (float*)mbuf;                       // 32*2048*64 fp32 = 16MB
    float* accL = accO + (size_t)32 * SEQ * HDIM;     // 32*2048 fp32
    (void)ws_size; (void)n_in; (void)in_sizes; (void)out_size;

    // converts + zero acc in one dispatch
    prep_kernel<<<16448, 256, 0, stream>>>(Wqkv, Wo_w, W1, W2,
                                           Wqkv_b, Wo_bf, W1_b, W2_b, accO);

    layernorm_kernel<<<NTOK, 256, 0, stream>>>(x, scale1, shift1, bufA);

    // merged QKV projection: N=3072, V columns transposed
    gemm_nt<0><<<dim3(3072 / 128, NTOK / 128), 256, 0, stream>>>(
        bufA, Wqkv_b, nullptr, nullptr, qb, kb, vtb, NTOK, 3072, D_MODEL, D_MODEL);

    attn_kernel<<<2560, 256, 0, stream>>>(qb, kb, vtb, accO, accL);
    attn_finalize<<<32 * SEQ * HDIM / 1024, 256, 0, stream>>>(accO, accL, bufA);

    // Wo: x1 = x + Wo_b, then split-K=2 atomic GEMM  x1 += attn * Wo^T
    init_bias_kernel<<<NTOK * D_MODEL / 1024, 256, 0, stream>>>(x, Wo_b, x1);
    gemm_nt<5><<<dim3(D_MODEL / 128, NTOK / 128, 2), 256, 0, stream>>>(
        bufA, Wo_bf, nullptr, x1, nullptr, nullptr, nullptr, NTOK, D_MODEL, D_MODEL, D_MODEL / 2);

    layernorm_kernel<<<NTOK, 256, 0, stream>>>(x1, scale2, shift2, qb);

    gemm_nt<2><<<dim3(FF_DIM / 128, NTOK / 128), 256, 0, stream>>>(
        qb, W1_b, b1, nullptr, mbuf, nullptr, nullptr, NTOK, FF_DIM, D_MODEL, D_MODEL);

    // W2: out = x1 + b2, then split-K=4 atomic GEMM  out += m * W2^T
    init_bias_kernel<<<NTOK * D_MODEL / 1024, 256, 0, stream>>>(x1, b2, out);
    gemm_nt<5><<<dim3(D_MODEL / 128, NTOK / 128, 4), 256, 0, stream>>>(
        mbuf, W2_b, nullptr, out, nullptr, nullptr, nullptr, NTOK, D_MODEL, FF_DIM, FF_DIM / 4);
}

// Round 6
// 419.007 us; speedup vs baseline: 1.0778x; 1.0778x over previous
//
#include <hip/hip_runtime.h>
#include <cstdint>
#include <cstddef>

typedef __bf16 bf16;
typedef __bf16 v8bf __attribute__((ext_vector_type(8)));
typedef __bf16 v4bf __attribute__((ext_vector_type(4)));
typedef float  v4f  __attribute__((ext_vector_type(4)));

#define D_MODEL 1024
#define FF_DIM  4096
#define SEQ     2048
#define NTOK    4096   // B*S
#define NH      16
#define HDIM    64

#define GLOAD_LDS16(g, l) \
    __builtin_amdgcn_global_load_lds((const __attribute__((address_space(1))) void*)(g), \
                                     (__attribute__((address_space(3))) void*)(l), 16, 0, 0)

// ---------------- prep: all weight converts, one dispatch ------
// float4 units: Wqkv 786432 | Wo 262144 | W1 1048576 | W2 1048576 -> 12288 blocks
__global__ __launch_bounds__(256) void prep_kernel(
    const float* __restrict__ Wqkv, const float* __restrict__ Wo,
    const float* __restrict__ W1, const float* __restrict__ W2,
    bf16* __restrict__ Wqkv_b, bf16* __restrict__ Wo_b,
    bf16* __restrict__ W1_b, bf16* __restrict__ W2_b) {
    int u = blockIdx.x * 256 + threadIdx.x;
    const float* src; bf16* dst; int idx;
    if (u < 786432)       { src = Wqkv; dst = Wqkv_b; idx = u * 4; }
    else if (u < 1048576) { src = Wo;   dst = Wo_b;   idx = (u - 786432) * 4; }
    else if (u < 2097152) { src = W1;   dst = W1_b;   idx = (u - 1048576) * 4; }
    else                  { src = W2;   dst = W2_b;   idx = (u - 2097152) * 4; }
    float4 v = *(const float4*)(src + idx);
    dst[idx + 0] = (bf16)v.x;
    dst[idx + 1] = (bf16)v.y;
    dst[idx + 2] = (bf16)v.z;
    dst[idx + 3] = (bf16)v.w;
}

// ---------------- LayerNorm (unbiased std, eps on std) ----------------
__global__ __launch_bounds__(256) void layernorm_kernel(
    const float* __restrict__ x, const float* __restrict__ scale,
    const float* __restrict__ shift, bf16* __restrict__ out) {
    int row = blockIdx.x;
    int t = threadIdx.x;
    const float* xr = x + (size_t)row * D_MODEL;
    float4 v = *(const float4*)(xr + t * 4);
    float s  = v.x + v.y + v.z + v.w;
    float sq = v.x * v.x + v.y * v.y + v.z * v.z + v.w * v.w;
    #pragma unroll
    for (int o = 1; o < 64; o <<= 1) {
        s  += __shfl_xor(s, o);
        sq += __shfl_xor(sq, o);
    }
    __shared__ float ws[8];
    int wv = t >> 6;
    if ((t & 63) == 0) { ws[wv * 2] = s; ws[wv * 2 + 1] = sq; }
    __syncthreads();
    s  = ws[0] + ws[2] + ws[4] + ws[6];
    sq = ws[1] + ws[3] + ws[5] + ws[7];
    float mean = s * (1.0f / D_MODEL);
    float var  = (sq - (float)D_MODEL * mean * mean) * (1.0f / (D_MODEL - 1));
    var = fmaxf(var, 0.0f);
    float inv = 1.0f / (sqrtf(var) + 1e-5f);
    #pragma unroll
    for (int j = 0; j < 4; ++j) {
        int c = t * 4 + j;
        float xv = (&v.x)[j];
        out[(size_t)row * D_MODEL + c] = (bf16)(shift[c] + scale[c] * (xv - mean) * inv);
    }
}

// ---------------- MFMA GEMM:  C[M,N] = A[M,K] * Bw[N,K]^T  ----------------
// global_load_lds width-16 staging, XOR-swizzled LDS chunks.
// EPI 0: QKV merged: cols<2048 -> q (x1/8) / k [BH,S,HD]; cols>=2048 -> V^T
// EPI 1: outf = resid + C + bias          (fp32 out)
// EPI 2: ob0 = gelu(C + bias)             (bf16 out, row stride N)
// EPI 6: ob0[z*M*N + row*N + col] = C     (bf16 partial, split-K)
template <int EPI>
__global__ __launch_bounds__(256) void gemm_nt(
    const bf16* __restrict__ A, const bf16* __restrict__ Bw,
    const float* __restrict__ bias, const float* __restrict__ resid,
    float* __restrict__ outf, bf16* __restrict__ ob0,
    bf16* __restrict__ ob1, bf16* __restrict__ ob2,
    int M, int N, int K, int klen) {
    __shared__ __align__(16) bf16 As[128 * 32];
    __shared__ __align__(16) bf16 Bs[128 * 32];
    int m0 = blockIdx.y * 128, n0 = blockIdx.x * 128;
    int kstart = blockIdx.z * klen;
    int t = threadIdx.x;
    int lane = t & 63, wave = t >> 6;
    int wm = wave >> 1, wn = wave & 1;
    int quad = lane >> 4, l16 = lane & 15;
    const bool trans = (EPI == 0) && (n0 >= 2048);

    int srow = lane >> 2;
    int schunk = (lane & 3) ^ (srow & 3);     // XOR swizzle
    const bf16* agp = A  + (size_t)(m0 + wave * 16 + srow) * K + kstart + schunk * 8;
    const bf16* bgp = Bw + (size_t)(n0 + wave * 16 + srow) * K + kstart + schunk * 8;
    bf16* aldst0 = &As[wave * 512];
    bf16* aldst1 = &As[(wave + 4) * 512];
    bf16* bldst0 = &Bs[wave * 512];
    bf16* bldst1 = &Bs[(wave + 4) * 512];

    v4f acc[4][4];
    #pragma unroll
    for (int i = 0; i < 4; ++i)
        #pragma unroll
        for (int j = 0; j < 4; ++j)
            acc[i][j] = (v4f){0.f, 0.f, 0.f, 0.f};

    int sw = l16 & 3;
    for (int kk = 0; kk < klen; kk += 32) {
        __syncthreads();
        GLOAD_LDS16(agp + kk,                  aldst0);
        GLOAD_LDS16(agp + (size_t)64 * K + kk, aldst1);
        GLOAD_LDS16(bgp + kk,                  bldst0);
        GLOAD_LDS16(bgp + (size_t)64 * K + kk, bldst1);
        __syncthreads();
        v8bf af[4], bfr[4];
        #pragma unroll
        for (int i = 0; i < 4; ++i)
            af[i] = *(const v8bf*)(&As[(wm * 64 + i * 16 + l16) * 32 + (quad ^ sw) * 8]);
        #pragma unroll
        for (int j = 0; j < 4; ++j)
            bfr[j] = *(const v8bf*)(&Bs[(wn * 64 + j * 16 + l16) * 32 + (quad ^ sw) * 8]);
        if (!trans) {
            #pragma unroll
            for (int i = 0; i < 4; ++i)
                #pragma unroll
                for (int j = 0; j < 4; ++j)
                    acc[i][j] = __builtin_amdgcn_mfma_f32_16x16x32_bf16(af[i], bfr[j], acc[i][j], 0, 0, 0);
        } else {
            #pragma unroll
            for (int i = 0; i < 4; ++i)
                #pragma unroll
                for (int j = 0; j < 4; ++j)
                    acc[i][j] = __builtin_amdgcn_mfma_f32_16x16x32_bf16(bfr[j], af[i], acc[i][j], 0, 0, 0);
        }
    }

    #pragma unroll
    for (int i = 0; i < 4; ++i) {
        #pragma unroll
        for (int j = 0; j < 4; ++j) {
            #pragma unroll
            for (int r = 0; r < 4; ++r) {
                float v = acc[i][j][r];
                if (EPI == 0) {
                    if (trans) {
                        int wrow = n0 + wn * 64 + j * 16 + quad * 4 + r;
                        int tok  = m0 + wm * 64 + i * 16 + l16;
                        int rr = wrow - 2048;
                        int h = rr >> 6, d = rr & 63;
                        int b = tok >> 11, sI = tok & 2047;
                        ob2[(((size_t)(b * NH + h)) * HDIM + d) * SEQ + sI] = (bf16)v;
                    } else {
                        int row = m0 + wm * 64 + i * 16 + quad * 4 + r;
                        int col = n0 + wn * 64 + j * 16 + l16;
                        int which = col >> 10, rr = col & 1023;
                        int h = rr >> 6, d = rr & 63;
                        int b = row >> 11, sI = row & 2047;
                        if (which == 0) {
                            ob0[(((size_t)(b * NH + h)) * SEQ + sI) * HDIM + d] = (bf16)(v * 0.125f);
                        } else {
                            ob1[(((size_t)(b * NH + h)) * SEQ + sI) * HDIM + d] = (bf16)v;
                        }
                    }
                } else {
                    int row = m0 + wm * 64 + i * 16 + quad * 4 + r;
                    int col = n0 + wn * 64 + j * 16 + l16;
                    if (EPI == 1) {
                        size_t o = (size_t)row * N + col;
                        outf[o] = resid[o] + v + bias[col];
                    } else if (EPI == 2) {
                        float u = v + bias[col];
                        float y = 1.5957691216057308f * (u + 0.044715f * u * u * u);
                        float g = u * __builtin_amdgcn_rcpf(1.0f + __expf(-y));
                        ob0[(size_t)row * N + col] = (bf16)g;
                    } else {   // EPI 6
                        ob0[(size_t)blockIdx.z * M * N + (size_t)row * N + col] = (bf16)v;
                    }
                }
            }
        }
    }
}

// ---------------- split-K=4 combine for W2: out = x1 + sum(p_z) + b2 --------
__global__ __launch_bounds__(256) void combine_w2(
    const bf16* __restrict__ part, const float* __restrict__ x1,
    const float* __restrict__ b2, float* __restrict__ out) {
    int i = (blockIdx.x * 256 + threadIdx.x) * 4;
    int col = i & (D_MODEL - 1);
    float4 xv = *(const float4*)(x1 + i);
    float4 bv = *(const float4*)(b2 + col);
    float4 r;
    r.x = xv.x + bv.x; r.y = xv.y + bv.y; r.z = xv.z + bv.z; r.w = xv.w + bv.w;
    #pragma unroll
    for (int z = 0; z < 4; ++z) {
        v4bf p = *(const v4bf*)(part + (size_t)z * NTOK * D_MODEL + i);
        r.x += (float)p[0]; r.y += (float)p[1]; r.z += (float)p[2]; r.w += (float)p[3];
    }
    *(float4*)(out + i) = r;
}

// ---------------- Flash attention (causal), 2-strip deterministic partials --
// Strips of 1024 keys. qtile<16 -> 1 strip, else 2. Each (bh,qtile,strip)
// block owns its 64 output rows: plain fp32 stores, no atomics.
__global__ __launch_bounds__(256) void attn_kernel(
    const bf16* __restrict__ qb, const bf16* __restrict__ kb,
    const bf16* __restrict__ vt, float* __restrict__ pO0,
    float* __restrict__ pO1, float* __restrict__ L0,
    float* __restrict__ L1) {
    int u = (int)gridDim.x - 1 - (int)blockIdx.x;   // heavy-first
    int bh = u / 48;
    int r48 = u - bh * 48;
    int qt, st;
    if (r48 < 16) { qt = r48; st = 0; }
    else          { qt = 16 + ((r48 - 16) >> 1); st = (r48 - 16) & 1; }
    int qbase = qt * 64;
    int kv0 = st * 1024;
    int kv1 = min(qbase + 64, kv0 + 1024);
    float* pO = st ? pO1 : pO0;
    float* L  = st ? L1 : L0;

    int t = threadIdx.x;
    int wave = t >> 6, lane = t & 63;
    int quad = lane >> 4, l16 = lane & 15;
    int qwb = qbase + wave * 16;

    const bf16* Qh  = qb + (size_t)bh * SEQ * HDIM;
    const bf16* Kh  = kb + (size_t)bh * SEQ * HDIM;
    const bf16* Vth = vt + (size_t)bh * HDIM * SEQ;

    __shared__ __align__(16) bf16 Ks[64 * 64];
    __shared__ __align__(16) bf16 Vs[64 * 64];
    __shared__ __align__(16) bf16 Ps[4][16 * 80];
    bf16* Pw = &Ps[wave][0];

    int u0 = t, u1 = t + 256;
    int key0 = u0 >> 3, c0 = (u0 & 7) ^ (key0 & 7);
    int key1 = u1 >> 3, c1 = (u1 & 7) ^ (key1 & 7);
    bf16* kdst0 = &Ks[wave * 512];
    bf16* kdst1 = &Ks[2048 + wave * 512];
    bf16* vdst0 = &Vs[wave * 512];
    bf16* vdst1 = &Vs[2048 + wave * 512];
    const bf16* Ksrc0 = Kh + (size_t)key0 * HDIM + c0 * 8;
    const bf16* Ksrc1 = Kh + (size_t)key1 * HDIM + c1 * 8;
    const bf16* Vsrc0 = Vth + (size_t)key0 * SEQ + c0 * 8;
    const bf16* Vsrc1 = Vth + (size_t)key1 * SEQ + c1 * 8;

    v8bf qf0 = *(const v8bf*)(Qh + (size_t)(qwb + l16) * HDIM + quad * 8);
    v8bf qf1 = *(const v8bf*)(Qh + (size_t)(qwb + l16) * HDIM + 32 + quad * 8);

    v4f o[4];
    #pragma unroll
    for (int dc = 0; dc < 4; ++dc) o[dc] = (v4f){0.f, 0.f, 0.f, 0.f};
    float lsum = 0.f;

    for (int kv = kv0; kv < kv1; kv += 64) {
        __syncthreads();
        GLOAD_LDS16(Ksrc0 + (size_t)kv * HDIM, kdst0);
        GLOAD_LDS16(Ksrc1 + (size_t)kv * HDIM, kdst1);
        GLOAD_LDS16(Vsrc0 + kv, vdst0);
        GLOAD_LDS16(Vsrc1 + kv, vdst1);
        __syncthreads();

        bool domask = (kv + 63 > qwb);
        #pragma unroll
        for (int j = 0; j < 4; ++j) {
            int key = j * 16 + l16;
            v8bf ka = *(const v8bf*)(&Ks[(key * 8 + (quad ^ (key & 7))) * 8]);
            v8bf kc = *(const v8bf*)(&Ks[(key * 8 + ((quad + 4) ^ (key & 7))) * 8]);
            v4f s = (v4f){-20.f, -20.f, -20.f, -20.f};
            s = __builtin_amdgcn_mfma_f32_16x16x32_bf16(ka, qf0, s, 0, 0, 0);
            s = __builtin_amdgcn_mfma_f32_16x16x32_bf16(kc, qf1, s, 0, 0, 0);
            int keyb = kv + j * 16 + quad * 4;
            union { bf16 h[4]; uint2 u; } pk;
            #pragma unroll
            for (int r = 0; r < 4; ++r) {
                float pv = __expf(s[r]);
                if (domask) pv = (keyb + r <= qwb + l16) ? pv : 0.f;
                lsum += pv;
                pk.h[r] = (bf16)pv;
            }
            *(uint2*)(&Pw[l16 * 80 + j * 16 + quad * 4]) = pk.u;
        }

        v8bf pf0 = *(const v8bf*)(&Pw[l16 * 80 + quad * 8]);
        v8bf pf1 = *(const v8bf*)(&Pw[l16 * 80 + 32 + quad * 8]);
        #pragma unroll
        for (int dc = 0; dc < 4; ++dc) {
            int dim = dc * 16 + l16;
            v8bf va = *(const v8bf*)(&Vs[(dim * 8 + (quad ^ (dim & 7))) * 8]);
            v8bf vc = *(const v8bf*)(&Vs[(dim * 8 + ((quad + 4) ^ (dim & 7))) * 8]);
            o[dc] = __builtin_amdgcn_mfma_f32_16x16x32_bf16(pf0, va, o[dc], 0, 0, 0);
            o[dc] = __builtin_amdgcn_mfma_f32_16x16x32_bf16(pf1, vc, o[dc], 0, 0, 0);
        }
    }

    lsum += __shfl_xor(lsum, 16);
    lsum += __shfl_xor(lsum, 32);
    if (quad == 0) L[(size_t)bh * SEQ + qwb + l16] = lsum;

    #pragma unroll
    for (int r = 0; r < 4; ++r) {
        int row = qwb + quad * 4 + r;
        #pragma unroll
        for (int dc = 0; dc < 4; ++dc) {
            pO[((size_t)bh * SEQ + row) * HDIM + dc * 16 + l16] = o[dc][r];
        }
    }
}

// ---------------- attention finalize: ob = (pO0 [+ pO1]) / (L0 [+ L1]) ------
__global__ __launch_bounds__(256) void attn_finalize(
    const float* __restrict__ pO0, const float* __restrict__ pO1,
    const float* __restrict__ L0, const float* __restrict__ L1,
    bf16* __restrict__ ob) {
    int i = (blockIdx.x * 256 + threadIdx.x) * 4;   // over 32*2048*64
    int bh = i >> 17;
    int rem = i & 131071;
    int s = rem >> 6, d0 = rem & 63;
    float l = L0[(size_t)bh * SEQ + s];
    float4 o = *(const float4*)(pO0 + i);
    if ((s >> 6) >= 16) {
        l += L1[(size_t)bh * SEQ + s];
        float4 o1 = *(const float4*)(pO1 + i);
        o.x += o1.x; o.y += o1.y; o.z += o1.z; o.w += o1.w;
    }
    float inv = 1.0f / l;
    int b = bh >> 4, h = bh & 15;
    bf16* dst = ob + ((size_t)(b * SEQ + s)) * D_MODEL + h * HDIM + d0;
    dst[0] = (bf16)(o.x * inv);
    dst[1] = (bf16)(o.y * inv);
    dst[2] = (bf16)(o.z * inv);
    dst[3] = (bf16)(o.w * inv);
}

// ---------------- launch ----------------
extern "C" void kernel_launch(void* const* d_in, const int* in_sizes, int n_in,
                              void* d_out, int out_size, void* d_ws, size_t ws_size,
                              hipStream_t stream) {
    const float* x      = (const float*)d_in[0];
    const float* scale1 = (const float*)d_in[1];
    const float* shift1 = (const float*)d_in[2];
    const float* Wqkv   = (const float*)d_in[3];
    const float* Wo_w   = (const float*)d_in[4];
    const float* Wo_b   = (const float*)d_in[5];
    const float* scale2 = (const float*)d_in[6];
    const float* shift2 = (const float*)d_in[7];
    const float* W1     = (const float*)d_in[8];
    const float* b1     = (const float*)d_in[9];
    const float* W2     = (const float*)d_in[10];
    const float* b2     = (const float*)d_in[11];
    float* out = (float*)d_out;

    char* ws = (char*)d_ws;
    size_t off = 0;
    auto alloc = [&](size_t bytes) -> char* {
        char* p = ws + off;
        off += (bytes + 255) & ~(size_t)255;
        return p;
    };
    bf16* Wqkv_b = (bf16*)alloc((size_t)3 * D_MODEL * D_MODEL * 2);
    bf16* Wo_bf  = (bf16*)alloc((size_t)D_MODEL * D_MODEL * 2);
    bf16* W1_b   = (bf16*)alloc((size_t)FF_DIM * D_MODEL * 2);
    bf16* W2_b   = (bf16*)alloc((size_t)D_MODEL * FF_DIM * 2);
    bf16* bufA   = (bf16*)alloc((size_t)NTOK * D_MODEL * 2);   // h1 / attn out
    bf16* qb     = (bf16*)alloc((size_t)NTOK * D_MODEL * 2);   // q / h2
    bf16* kb     = (bf16*)alloc((size_t)NTOK * D_MODEL * 2);
    bf16* vtb    = (bf16*)alloc((size_t)NTOK * D_MODEL * 2);   // V transposed
    float* x1    = (float*)alloc((size_t)NTOK * D_MODEL * 4);
    bf16* mbuf   = (bf16*)alloc((size_t)NTOK * FF_DIM * 2);
    // attention partials: slot0+Ls alias mbuf (dead until W1), slot1 aliases x1
    // (x1 written only later, by Wo EPI-1)
    float* pO0 = (float*)mbuf;                            // 16.78 MB
    float* L0  = pO0 + (size_t)32 * SEQ * HDIM;           // 256 KB
    float* L1  = L0 + (size_t)32 * SEQ;
    float* pO1 = x1;                                      // exactly 16.78 MB
    // W2 bf16 partials: 4 x 8.39 MB = exactly bufA..vtb (dead by then)
    bf16* w2part = bufA;
    (void)ws_size; (void)n_in; (void)in_sizes; (void)out_size;

    prep_kernel<<<12288, 256, 0, stream>>>(Wqkv, Wo_w, W1, W2,
                                           Wqkv_b, Wo_bf, W1_b, W2_b);

    layernorm_kernel<<<NTOK, 256, 0, stream>>>(x, scale1, shift1, bufA);

    // merged QKV projection: N=3072, V columns transposed
    gemm_nt<0><<<dim3(3072 / 128, NTOK / 128), 256, 0, stream>>>(
        bufA, Wqkv_b, nullptr, nullptr, nullptr, qb, kb, vtb, NTOK, 3072, D_MODEL, D_MODEL);

    attn_kernel<<<1536, 256, 0, stream>>>(qb, kb, vtb, pO0, pO1, L0, L1);
    attn_finalize<<<32 * SEQ * HDIM / 1024, 256, 0, stream>>>(pO0, pO1, L0, L1, bufA);

    // Wo: x1 = x + attn*Wo^T + Wo_b  (overwrites pO1 alias — attn partials dead)
    gemm_nt<1><<<dim3(D_MODEL / 128, NTOK / 128), 256, 0, stream>>>(
        bufA, Wo_bf, Wo_b, x, x1, nullptr, nullptr, nullptr, NTOK, D_MODEL, D_MODEL, D_MODEL);

    layernorm_kernel<<<NTOK, 256, 0, stream>>>(x1, scale2, shift2, qb);

    gemm_nt<2><<<dim3(FF_DIM / 128, NTOK / 128), 256, 0, stream>>>(
        qb, W1_b, b1, nullptr, nullptr, mbuf, nullptr, nullptr, NTOK, FF_DIM, D_MODEL, D_MODEL);

    // W2 split-K=4, bf16 partials, then combine
    gemm_nt<6><<<dim3(D_MODEL / 128, NTOK / 128, 4), 256, 0, stream>>>(
        mbuf, W2_b, nullptr, nullptr, nullptr, w2part, nullptr, nullptr, NTOK, D_MODEL, FF_DIM, FF_DIM / 4);

    combine_w2<<<NTOK * D_MODEL / 1024, 256, 0, stream>>>(w2part, x1, b2, out);
}

// Round 7
// 361.394 us; speedup vs baseline: 1.2497x; 1.1594x over previous
//
#include <hip/hip_runtime.h>
#include <cstdint>
#include <cstddef>

typedef __bf16 bf16;
typedef __bf16 v8bf __attribute__((ext_vector_type(8)));
typedef __bf16 v4bf __attribute__((ext_vector_type(4)));
typedef float  v4f  __attribute__((ext_vector_type(4)));

#define D_MODEL 1024
#define FF_DIM  4096
#define SEQ     2048
#define NTOK    4096   // B*S
#define NH      16
#define HDIM    64

#define GLOAD_LDS16(g, l) \
    __builtin_amdgcn_global_load_lds((const __attribute__((address_space(1))) void*)(g), \
                                     (__attribute__((address_space(3))) void*)(l), 16, 0, 0)

// ---------------- prep: all weight converts, one dispatch ------
__global__ __launch_bounds__(256) void prep_kernel(
    const float* __restrict__ Wqkv, const float* __restrict__ Wo,
    const float* __restrict__ W1, const float* __restrict__ W2,
    bf16* __restrict__ Wqkv_b, bf16* __restrict__ Wo_b,
    bf16* __restrict__ W1_b, bf16* __restrict__ W2_b) {
    int u = blockIdx.x * 256 + threadIdx.x;
    const float* src; bf16* dst; int idx;
    if (u < 786432)       { src = Wqkv; dst = Wqkv_b; idx = u * 4; }
    else if (u < 1048576) { src = Wo;   dst = Wo_b;   idx = (u - 786432) * 4; }
    else if (u < 2097152) { src = W1;   dst = W1_b;   idx = (u - 1048576) * 4; }
    else                  { src = W2;   dst = W2_b;   idx = (u - 2097152) * 4; }
    float4 v = *(const float4*)(src + idx);
    dst[idx + 0] = (bf16)v.x;
    dst[idx + 1] = (bf16)v.y;
    dst[idx + 2] = (bf16)v.z;
    dst[idx + 3] = (bf16)v.w;
}

// ---------------- LayerNorm (unbiased std, eps on std) ----------------
__global__ __launch_bounds__(256) void layernorm_kernel(
    const float* __restrict__ x, const float* __restrict__ scale,
    const float* __restrict__ shift, bf16* __restrict__ out) {
    int row = blockIdx.x;
    int t = threadIdx.x;
    const float* xr = x + (size_t)row * D_MODEL;
    float4 v = *(const float4*)(xr + t * 4);
    float s  = v.x + v.y + v.z + v.w;
    float sq = v.x * v.x + v.y * v.y + v.z * v.z + v.w * v.w;
    #pragma unroll
    for (int o = 1; o < 64; o <<= 1) {
        s  += __shfl_xor(s, o);
        sq += __shfl_xor(sq, o);
    }
    __shared__ float ws[8];
    int wv = t >> 6;
    if ((t & 63) == 0) { ws[wv * 2] = s; ws[wv * 2 + 1] = sq; }
    __syncthreads();
    s  = ws[0] + ws[2] + ws[4] + ws[6];
    sq = ws[1] + ws[3] + ws[5] + ws[7];
    float mean = s * (1.0f / D_MODEL);
    float var  = (sq - (float)D_MODEL * mean * mean) * (1.0f / (D_MODEL - 1));
    var = fmaxf(var, 0.0f);
    float inv = 1.0f / (sqrtf(var) + 1e-5f);
    #pragma unroll
    for (int j = 0; j < 4; ++j) {
        int c = t * 4 + j;
        float xv = (&v.x)[j];
        out[(size_t)row * D_MODEL + c] = (bf16)(shift[c] + scale[c] * (xv - mean) * inv);
    }
}

// ---------------- V transpose: [BH,S,HD] -> [BH,HD,S], 64x64 tiles ----------
__global__ __launch_bounds__(256) void transpose_v(
    const bf16* __restrict__ vb, bf16* __restrict__ vt) {
    int bh = blockIdx.x >> 5;
    int ts = blockIdx.x & 31;
    int t = threadIdx.x;
    __shared__ bf16 T[64][72];
    const bf16* src = vb + ((size_t)bh * SEQ + ts * 64) * HDIM;
    #pragma unroll
    for (int half = 0; half < 2; ++half) {
        int s = (t >> 3) + half * 32;
        int d0 = (t & 7) * 8;
        v8bf vv = *(const v8bf*)(src + (size_t)s * HDIM + d0);
        #pragma unroll
        for (int j = 0; j < 8; ++j) T[d0 + j][s] = vv[j];
    }
    __syncthreads();
    bf16* dst = vt + (size_t)bh * HDIM * SEQ + ts * 64;
    int d = t >> 2;
    #pragma unroll
    for (int cc = 0; cc < 2; ++cc) {
        int c = (t & 3) + cc * 4;
        v8bf o = *(const v8bf*)(&T[d][c * 8]);
        *(v8bf*)(dst + (size_t)d * SEQ + c * 8) = o;
    }
}

// ---------------- MFMA GEMM:  C[M,N] = A[M,K] * Bw[N,K]^T  ----------------
// BK=64, global_load_lds width-16 staging, XOR-swizzled LDS (chunk ^= row&7).
// EPI 0: QKV: col<1024 -> q (x1/8), <2048 -> k, else -> v   (all [BH,S,HD])
// EPI 1: outf = resid + C + bias          (fp32 out)
// EPI 2: ob0 = gelu(C + bias)             (bf16 out, row stride N)
// EPI 6: ob0[z*M*N + row*N + col] = C     (bf16 partial, split-K)
template <int EPI>
__global__ __launch_bounds__(256) void gemm_nt(
    const bf16* __restrict__ A, const bf16* __restrict__ Bw,
    const float* __restrict__ bias, const float* __restrict__ resid,
    float* __restrict__ outf, bf16* __restrict__ ob0,
    bf16* __restrict__ ob1, bf16* __restrict__ ob2,
    int M, int N, int K, int klen) {
    __shared__ __align__(16) bf16 As[128 * 64];
    __shared__ __align__(16) bf16 Bs[128 * 64];
    int m0 = blockIdx.y * 128, n0 = blockIdx.x * 128;
    int kstart = blockIdx.z * klen;
    int t = threadIdx.x;
    int lane = t & 63, wave = t >> 6;
    int wm = wave >> 1, wn = wave & 1;
    int quad = lane >> 4, l16 = lane & 15;

    // staging: issue ii covers rows ii*32 + wave*8 + (lane>>3), chunk (lane&7)
    // physical LDS chunk = logical, so read global from logical = phys ^ (row&7)
    int srow8 = lane >> 3;                   // row mod 8 within the 8-row group
    int schunk = (lane & 7) ^ srow8;         // XOR swizzle
    const bf16* agp = A  + (size_t)(m0 + wave * 8 + srow8) * K + kstart + schunk * 8;
    const bf16* bgp = Bw + (size_t)(n0 + wave * 8 + srow8) * K + kstart + schunk * 8;
    size_t row32 = (size_t)32 * K;

    v4f acc[4][4];
    #pragma unroll
    for (int i = 0; i < 4; ++i)
        #pragma unroll
        for (int j = 0; j < 4; ++j)
            acc[i][j] = (v4f){0.f, 0.f, 0.f, 0.f};

    int rsw = l16 & 7;
    for (int kk = 0; kk < klen; kk += 64) {
        __syncthreads();
        #pragma unroll
        for (int ii = 0; ii < 4; ++ii) {
            GLOAD_LDS16(agp + ii * row32 + kk, &As[ii * 2048 + wave * 512]);
            GLOAD_LDS16(bgp + ii * row32 + kk, &Bs[ii * 2048 + wave * 512]);
        }
        __syncthreads();
        #pragma unroll
        for (int h = 0; h < 2; ++h) {
            v8bf af[4], bfr[4];
            #pragma unroll
            for (int i = 0; i < 4; ++i)
                af[i] = *(const v8bf*)(&As[(wm * 64 + i * 16 + l16) * 64 + (((h * 4 + quad) ^ rsw)) * 8]);
            #pragma unroll
            for (int j = 0; j < 4; ++j)
                bfr[j] = *(const v8bf*)(&Bs[(wn * 64 + j * 16 + l16) * 64 + (((h * 4 + quad) ^ rsw)) * 8]);
            #pragma unroll
            for (int i = 0; i < 4; ++i)
                #pragma unroll
                for (int j = 0; j < 4; ++j)
                    acc[i][j] = __builtin_amdgcn_mfma_f32_16x16x32_bf16(af[i], bfr[j], acc[i][j], 0, 0, 0);
        }
    }

    #pragma unroll
    for (int i = 0; i < 4; ++i) {
        #pragma unroll
        for (int j = 0; j < 4; ++j) {
            #pragma unroll
            for (int r = 0; r < 4; ++r) {
                float v = acc[i][j][r];
                int row = m0 + wm * 64 + i * 16 + quad * 4 + r;
                int col = n0 + wn * 64 + j * 16 + l16;
                if (EPI == 0) {
                    int which = col >> 10, rr = col & 1023;
                    int h = rr >> 6, d = rr & 63;
                    int b = row >> 11, sI = row & 2047;
                    size_t dst = (((size_t)(b * NH + h)) * SEQ + sI) * HDIM + d;
                    if (which == 0)      ob0[dst] = (bf16)(v * 0.125f);
                    else if (which == 1) ob1[dst] = (bf16)v;
                    else                 ob2[dst] = (bf16)v;
                } else if (EPI == 1) {
                    size_t o = (size_t)row * N + col;
                    outf[o] = resid[o] + v + bias[col];
                } else if (EPI == 2) {
                    float u = v + bias[col];
                    float y = 1.5957691216057308f * (u + 0.044715f * u * u * u);
                    float g = u * __builtin_amdgcn_rcpf(1.0f + __expf(-y));
                    ob0[(size_t)row * N + col] = (bf16)g;
                } else {   // EPI 6
                    ob0[(size_t)blockIdx.z * M * N + (size_t)row * N + col] = (bf16)v;
                }
            }
        }
    }
}

// ---------------- split-K=4 combine for W2: out = x1 + sum(p_z) + b2 --------
__global__ __launch_bounds__(256) void combine_w2(
    const bf16* __restrict__ part, const float* __restrict__ x1,
    const float* __restrict__ b2, float* __restrict__ out) {
    int i = (blockIdx.x * 256 + threadIdx.x) * 4;
    int col = i & (D_MODEL - 1);
    float4 xv = *(const float4*)(x1 + i);
    float4 bv = *(const float4*)(b2 + col);
    float4 r;
    r.x = xv.x + bv.x; r.y = xv.y + bv.y; r.z = xv.z + bv.z; r.w = xv.w + bv.w;
    #pragma unroll
    for (int z = 0; z < 4; ++z) {
        v4bf p = *(const v4bf*)(part + (size_t)z * NTOK * D_MODEL + i);
        r.x += (float)p[0]; r.y += (float)p[1]; r.z += (float)p[2]; r.w += (float)p[3];
    }
    *(float4*)(out + i) = r;
}

// ---------------- Flash attention (causal), 2-strip deterministic partials --
__global__ __launch_bounds__(256) void attn_kernel(
    const bf16* __restrict__ qb, const bf16* __restrict__ kb,
    const bf16* __restrict__ vt, float* __restrict__ pO0,
    float* __restrict__ pO1, float* __restrict__ L0,
    float* __restrict__ L1) {
    int u = (int)gridDim.x - 1 - (int)blockIdx.x;   // heavy-first
    int bh = u / 48;
    int r48 = u - bh * 48;
    int qt, st;
    if (r48 < 16) { qt = r48; st = 0; }
    else          { qt = 16 + ((r48 - 16) >> 1); st = (r48 - 16) & 1; }
    int qbase = qt * 64;
    int kv0 = st * 1024;
    int kv1 = min(qbase + 64, kv0 + 1024);
    float* pO = st ? pO1 : pO0;
    float* L  = st ? L1 : L0;

    int t = threadIdx.x;
    int wave = t >> 6, lane = t & 63;
    int quad = lane >> 4, l16 = lane & 15;
    int qwb = qbase + wave * 16;

    const bf16* Qh  = qb + (size_t)bh * SEQ * HDIM;
    const bf16* Kh  = kb + (size_t)bh * SEQ * HDIM;
    const bf16* Vth = vt + (size_t)bh * HDIM * SEQ;

    __shared__ __align__(16) bf16 Ks[64 * 64];
    __shared__ __align__(16) bf16 Vs[64 * 64];
    __shared__ __align__(16) bf16 Ps[4][16 * 80];
    bf16* Pw = &Ps[wave][0];

    int u0 = t, u1 = t + 256;
    int key0 = u0 >> 3, c0 = (u0 & 7) ^ (key0 & 7);
    int key1 = u1 >> 3, c1 = (u1 & 7) ^ (key1 & 7);
    bf16* kdst0 = &Ks[wave * 512];
    bf16* kdst1 = &Ks[2048 + wave * 512];
    bf16* vdst0 = &Vs[wave * 512];
    bf16* vdst1 = &Vs[2048 + wave * 512];
    const bf16* Ksrc0 = Kh + (size_t)key0 * HDIM + c0 * 8;
    const bf16* Ksrc1 = Kh + (size_t)key1 * HDIM + c1 * 8;
    const bf16* Vsrc0 = Vth + (size_t)key0 * SEQ + c0 * 8;
    const bf16* Vsrc1 = Vth + (size_t)key1 * SEQ + c1 * 8;

    v8bf qf0 = *(const v8bf*)(Qh + (size_t)(qwb + l16) * HDIM + quad * 8);
    v8bf qf1 = *(const v8bf*)(Qh + (size_t)(qwb + l16) * HDIM + 32 + quad * 8);

    v4f o[4];
    #pragma unroll
    for (int dc = 0; dc < 4; ++dc) o[dc] = (v4f){0.f, 0.f, 0.f, 0.f};
    float lsum = 0.f;

    for (int kv = kv0; kv < kv1; kv += 64) {
        __syncthreads();
        GLOAD_LDS16(Ksrc0 + (size_t)kv * HDIM, kdst0);
        GLOAD_LDS16(Ksrc1 + (size_t)kv * HDIM, kdst1);
        GLOAD_LDS16(Vsrc0 + kv, vdst0);
        GLOAD_LDS16(Vsrc1 + kv, vdst1);
        __syncthreads();

        bool domask = (kv + 63 > qwb);
        #pragma unroll
        for (int j = 0; j < 4; ++j) {
            int key = j * 16 + l16;
            v8bf ka = *(const v8bf*)(&Ks[(key * 8 + (quad ^ (key & 7))) * 8]);
            v8bf kc = *(const v8bf*)(&Ks[(key * 8 + ((quad + 4) ^ (key & 7))) * 8]);
            v4f s = (v4f){-20.f, -20.f, -20.f, -20.f};
            s = __builtin_amdgcn_mfma_f32_16x16x32_bf16(ka, qf0, s, 0, 0, 0);
            s = __builtin_amdgcn_mfma_f32_16x16x32_bf16(kc, qf1, s, 0, 0, 0);
            int keyb = kv + j * 16 + quad * 4;
            union { bf16 h[4]; uint2 u; } pk;
            #pragma unroll
            for (int r = 0; r < 4; ++r) {
                float pv = __expf(s[r]);
                if (domask) pv = (keyb + r <= qwb + l16) ? pv : 0.f;
                lsum += pv;
                pk.h[r] = (bf16)pv;
            }
            *(uint2*)(&Pw[l16 * 80 + j * 16 + quad * 4]) = pk.u;
        }

        v8bf pf0 = *(const v8bf*)(&Pw[l16 * 80 + quad * 8]);
        v8bf pf1 = *(const v8bf*)(&Pw[l16 * 80 + 32 + quad * 8]);
        #pragma unroll
        for (int dc = 0; dc < 4; ++dc) {
            int dim = dc * 16 + l16;
            v8bf va = *(const v8bf*)(&Vs[(dim * 8 + (quad ^ (dim & 7))) * 8]);
            v8bf vc = *(const v8bf*)(&Vs[(dim * 8 + ((quad + 4) ^ (dim & 7))) * 8]);
            o[dc] = __builtin_amdgcn_mfma_f32_16x16x32_bf16(pf0, va, o[dc], 0, 0, 0);
            o[dc] = __builtin_amdgcn_mfma_f32_16x16x32_bf16(pf1, vc, o[dc], 0, 0, 0);
        }
    }

    lsum += __shfl_xor(lsum, 16);
    lsum += __shfl_xor(lsum, 32);
    if (quad == 0) L[(size_t)bh * SEQ + qwb + l16] = lsum;

    #pragma unroll
    for (int r = 0; r < 4; ++r) {
        int row = qwb + quad * 4 + r;
        #pragma unroll
        for (int dc = 0; dc < 4; ++dc) {
            pO[((size_t)bh * SEQ + row) * HDIM + dc * 16 + l16] = o[dc][r];
        }
    }
}

// ---------------- attention finalize: ob = (pO0 [+ pO1]) / (L0 [+ L1]) ------
__global__ __launch_bounds__(256) void attn_finalize(
    const float* __restrict__ pO0, const float* __restrict__ pO1,
    const float* __restrict__ L0, const float* __restrict__ L1,
    bf16* __restrict__ ob) {
    int i = (blockIdx.x * 256 + threadIdx.x) * 4;   // over 32*2048*64
    int bh = i >> 17;
    int rem = i & 131071;
    int s = rem >> 6, d0 = rem & 63;
    float l = L0[(size_t)bh * SEQ + s];
    float4 o = *(const float4*)(pO0 + i);
    if ((s >> 6) >= 16) {
        l += L1[(size_t)bh * SEQ + s];
        float4 o1 = *(const float4*)(pO1 + i);
        o.x += o1.x; o.y += o1.y; o.z += o1.z; o.w += o1.w;
    }
    float inv = 1.0f / l;
    int b = bh >> 4, h = bh & 15;
    bf16* dst = ob + ((size_t)(b * SEQ + s)) * D_MODEL + h * HDIM + d0;
    dst[0] = (bf16)(o.x * inv);
    dst[1] = (bf16)(o.y * inv);
    dst[2] = (bf16)(o.z * inv);
    dst[3] = (bf16)(o.w * inv);
}

// ---------------- launch ----------------
extern "C" void kernel_launch(void* const* d_in, const int* in_sizes, int n_in,
                              void* d_out, int out_size, void* d_ws, size_t ws_size,
                              hipStream_t stream) {
    const float* x      = (const float*)d_in[0];
    const float* scale1 = (const float*)d_in[1];
    const float* shift1 = (const float*)d_in[2];
    const float* Wqkv   = (const float*)d_in[3];
    const float* Wo_w   = (const float*)d_in[4];
    const float* Wo_b   = (const float*)d_in[5];
    const float* scale2 = (const float*)d_in[6];
    const float* shift2 = (const float*)d_in[7];
    const float* W1     = (const float*)d_in[8];
    const float* b1     = (const float*)d_in[9];
    const float* W2     = (const float*)d_in[10];
    const float* b2     = (const float*)d_in[11];
    float* out = (float*)d_out;

    char* ws = (char*)d_ws;
    size_t off = 0;
    auto alloc = [&](size_t bytes) -> char* {
        char* p = ws + off;
        off += (bytes + 255) & ~(size_t)255;
        return p;
    };
    bf16* Wqkv_b = (bf16*)alloc((size_t)3 * D_MODEL * D_MODEL * 2);
    bf16* Wo_bf  = (bf16*)alloc((size_t)D_MODEL * D_MODEL * 2);
    bf16* W1_b   = (bf16*)alloc((size_t)FF_DIM * D_MODEL * 2);
    bf16* W2_b   = (bf16*)alloc((size_t)D_MODEL * FF_DIM * 2);
    bf16* bufA   = (bf16*)alloc((size_t)NTOK * D_MODEL * 2);   // h1 / attn out
    bf16* qb     = (bf16*)alloc((size_t)NTOK * D_MODEL * 2);   // q / h2
    bf16* kb     = (bf16*)alloc((size_t)NTOK * D_MODEL * 2);
    bf16* vb     = (bf16*)alloc((size_t)NTOK * D_MODEL * 2);   // V normal layout
    bf16* vtb    = (bf16*)alloc((size_t)NTOK * D_MODEL * 2);   // V transposed
    float* x1    = (float*)alloc((size_t)NTOK * D_MODEL * 4);
    bf16* mbuf   = (bf16*)alloc((size_t)NTOK * FF_DIM * 2);
    // attention partials: slot0+Ls alias mbuf (dead until W1), slot1 aliases x1
    float* pO0 = (float*)mbuf;                            // 16.78 MB
    float* L0  = pO0 + (size_t)32 * SEQ * HDIM;
    float* L1  = L0 + (size_t)32 * SEQ;
    float* pO1 = x1;
    // W2 bf16 partials: 4 x 8.39 MB = bufA..vb (dead by then)
    bf16* w2part = bufA;
    (void)ws_size; (void)n_in; (void)in_sizes; (void)out_size;

    prep_kernel<<<12288, 256, 0, stream>>>(Wqkv, Wo_w, W1, W2,
                                           Wqkv_b, Wo_bf, W1_b, W2_b);

    layernorm_kernel<<<NTOK, 256, 0, stream>>>(x, scale1, shift1, bufA);

    // merged QKV projection: N=3072, all normal orientation
    gemm_nt<0><<<dim3(3072 / 128, NTOK / 128), 256, 0, stream>>>(
        bufA, Wqkv_b, nullptr, nullptr, nullptr, qb, kb, vb, NTOK, 3072, D_MODEL, D_MODEL);

    transpose_v<<<1024, 256, 0, stream>>>(vb, vtb);

    attn_kernel<<<1536, 256, 0, stream>>>(qb, kb, vtb, pO0, pO1, L0, L1);
    attn_finalize<<<32 * SEQ * HDIM / 1024, 256, 0, stream>>>(pO0, pO1, L0, L1, bufA);

    // Wo: x1 = x + attn*Wo^T + Wo_b  (overwrites pO1 alias — attn partials dead)
    gemm_nt<1><<<dim3(D_MODEL / 128, NTOK / 128), 256, 0, stream>>>(
        bufA, Wo_bf, Wo_b, x, x1, nullptr, nullptr, nullptr, NTOK, D_MODEL, D_MODEL, D_MODEL);

    layernorm_kernel<<<NTOK, 256, 0, stream>>>(x1, scale2, shift2, qb);

    gemm_nt<2><<<dim3(FF_DIM / 128, NTOK / 128), 256, 0, stream>>>(
        qb, W1_b, b1, nullptr, nullptr, mbuf, nullptr, nullptr, NTOK, FF_DIM, D_MODEL, D_MODEL);

    // W2 split-K=4, bf16 partials, then combine
    gemm_nt<6><<<dim3(D_MODEL / 128, NTOK / 128, 4), 256, 0, stream>>>(
        mbuf, W2_b, nullptr, nullptr, nullptr, w2part, nullptr, nullptr, NTOK, D_MODEL, FF_DIM, FF_DIM / 4);

    combine_w2<<<NTOK * D_MODEL / 1024, 256, 0, stream>>>(w2part, x1, b2, out);
}

// Round 8
// 360.837 us; speedup vs baseline: 1.2516x; 1.0015x over previous
//
#include <hip/hip_runtime.h>
#include <cstdint>
#include <cstddef>

typedef __bf16 bf16;
typedef __bf16 v8bf __attribute__((ext_vector_type(8)));
typedef __bf16 v4bf __attribute__((ext_vector_type(4)));
typedef float  v4f  __attribute__((ext_vector_type(4)));

#define D_MODEL 1024
#define FF_DIM  4096
#define SEQ     2048
#define NTOK    4096   // B*S
#define NH      16
#define HDIM    64

#define GLOAD_LDS16(g, l) \
    __builtin_amdgcn_global_load_lds((const __attribute__((address_space(1))) void*)(g), \
                                     (__attribute__((address_space(3))) void*)(l), 16, 0, 0)

// q prescale: 1/8 * log2(e) so softmax uses raw exp2
#define QSCALE 0.18033688011112042f
// shift: -20 * log2(e)
#define SHIFT2 -28.853900817779268f

// ---------------- prep: all weight converts, one dispatch ------
__global__ __launch_bounds__(256) void prep_kernel(
    const float* __restrict__ Wqkv, const float* __restrict__ Wo,
    const float* __restrict__ W1, const float* __restrict__ W2,
    bf16* __restrict__ Wqkv_b, bf16* __restrict__ Wo_b,
    bf16* __restrict__ W1_b, bf16* __restrict__ W2_b) {
    int u = blockIdx.x * 256 + threadIdx.x;
    const float* src; bf16* dst; int idx;
    if (u < 786432)       { src = Wqkv; dst = Wqkv_b; idx = u * 4; }
    else if (u < 1048576) { src = Wo;   dst = Wo_b;   idx = (u - 786432) * 4; }
    else if (u < 2097152) { src = W1;   dst = W1_b;   idx = (u - 1048576) * 4; }
    else                  { src = W2;   dst = W2_b;   idx = (u - 2097152) * 4; }
    float4 v = *(const float4*)(src + idx);
    dst[idx + 0] = (bf16)v.x;
    dst[idx + 1] = (bf16)v.y;
    dst[idx + 2] = (bf16)v.z;
    dst[idx + 3] = (bf16)v.w;
}

// ---------------- LayerNorm (unbiased std, eps on std) ----------------
__global__ __launch_bounds__(256) void layernorm_kernel(
    const float* __restrict__ x, const float* __restrict__ scale,
    const float* __restrict__ shift, bf16* __restrict__ out) {
    int row = blockIdx.x;
    int t = threadIdx.x;
    const float* xr = x + (size_t)row * D_MODEL;
    float4 v = *(const float4*)(xr + t * 4);
    float s  = v.x + v.y + v.z + v.w;
    float sq = v.x * v.x + v.y * v.y + v.z * v.z + v.w * v.w;
    #pragma unroll
    for (int o = 1; o < 64; o <<= 1) {
        s  += __shfl_xor(s, o);
        sq += __shfl_xor(sq, o);
    }
    __shared__ float ws[8];
    int wv = t >> 6;
    if ((t & 63) == 0) { ws[wv * 2] = s; ws[wv * 2 + 1] = sq; }
    __syncthreads();
    s  = ws[0] + ws[2] + ws[4] + ws[6];
    sq = ws[1] + ws[3] + ws[5] + ws[7];
    float mean = s * (1.0f / D_MODEL);
    float var  = (sq - (float)D_MODEL * mean * mean) * (1.0f / (D_MODEL - 1));
    var = fmaxf(var, 0.0f);
    float inv = 1.0f / (sqrtf(var) + 1e-5f);
    #pragma unroll
    for (int j = 0; j < 4; ++j) {
        int c = t * 4 + j;
        float xv = (&v.x)[j];
        out[(size_t)row * D_MODEL + c] = (bf16)(shift[c] + scale[c] * (xv - mean) * inv);
    }
}

// ---------------- V transpose: [BH,S,HD] -> [BH,HD,S], 64x64 tiles ----------
__global__ __launch_bounds__(256) void transpose_v(
    const bf16* __restrict__ vb, bf16* __restrict__ vt) {
    int bh = blockIdx.x >> 5;
    int ts = blockIdx.x & 31;
    int t = threadIdx.x;
    __shared__ bf16 T[64][72];
    const bf16* src = vb + ((size_t)bh * SEQ + ts * 64) * HDIM;
    #pragma unroll
    for (int half = 0; half < 2; ++half) {
        int s = (t >> 3) + half * 32;
        int d0 = (t & 7) * 8;
        v8bf vv = *(const v8bf*)(src + (size_t)s * HDIM + d0);
        #pragma unroll
        for (int j = 0; j < 8; ++j) T[d0 + j][s] = vv[j];
    }
    __syncthreads();
    bf16* dst = vt + (size_t)bh * HDIM * SEQ + ts * 64;
    int d = t >> 2;
    #pragma unroll
    for (int cc = 0; cc < 2; ++cc) {
        int c = (t & 3) + cc * 4;
        v8bf o = *(const v8bf*)(&T[d][c * 8]);
        *(v8bf*)(dst + (size_t)d * SEQ + c * 8) = o;
    }
}

// ---------------- MFMA GEMM:  C[M,N] = A[M,K] * Bw[N,K]^T  ----------------
// BK=64, global_load_lds width-16 staging, XOR-swizzled LDS (chunk ^= row&7).
// EPI 0: QKV: col<1024 -> q (xQSCALE), <2048 -> k, else -> v   (all [BH,S,HD])
// EPI 1: outf = resid + C + bias          (fp32 out)
// EPI 2: ob0 = gelu(C + bias)             (bf16 out, row stride N)
// EPI 6: ob0[z*M*N + row*N + col] = C     (bf16 partial, split-K)
template <int EPI>
__global__ __launch_bounds__(256) void gemm_nt(
    const bf16* __restrict__ A, const bf16* __restrict__ Bw,
    const float* __restrict__ bias, const float* __restrict__ resid,
    float* __restrict__ outf, bf16* __restrict__ ob0,
    bf16* __restrict__ ob1, bf16* __restrict__ ob2,
    int M, int N, int K, int klen) {
    __shared__ __align__(16) bf16 As[128 * 64];
    __shared__ __align__(16) bf16 Bs[128 * 64];
    int m0 = blockIdx.y * 128, n0 = blockIdx.x * 128;
    int kstart = blockIdx.z * klen;
    int t = threadIdx.x;
    int lane = t & 63, wave = t >> 6;
    int wm = wave >> 1, wn = wave & 1;
    int quad = lane >> 4, l16 = lane & 15;

    int srow8 = lane >> 3;
    int schunk = (lane & 7) ^ srow8;         // XOR swizzle
    const bf16* agp = A  + (size_t)(m0 + wave * 8 + srow8) * K + kstart + schunk * 8;
    const bf16* bgp = Bw + (size_t)(n0 + wave * 8 + srow8) * K + kstart + schunk * 8;
    size_t row32 = (size_t)32 * K;

    v4f acc[4][4];
    #pragma unroll
    for (int i = 0; i < 4; ++i)
        #pragma unroll
        for (int j = 0; j < 4; ++j)
            acc[i][j] = (v4f){0.f, 0.f, 0.f, 0.f};

    int rsw = l16 & 7;
    for (int kk = 0; kk < klen; kk += 64) {
        __syncthreads();
        #pragma unroll
        for (int ii = 0; ii < 4; ++ii) {
            GLOAD_LDS16(agp + ii * row32 + kk, &As[ii * 2048 + wave * 512]);
            GLOAD_LDS16(bgp + ii * row32 + kk, &Bs[ii * 2048 + wave * 512]);
        }
        __syncthreads();
        #pragma unroll
        for (int h = 0; h < 2; ++h) {
            v8bf af[4], bfr[4];
            #pragma unroll
            for (int i = 0; i < 4; ++i)
                af[i] = *(const v8bf*)(&As[(wm * 64 + i * 16 + l16) * 64 + (((h * 4 + quad) ^ rsw)) * 8]);
            #pragma unroll
            for (int j = 0; j < 4; ++j)
                bfr[j] = *(const v8bf*)(&Bs[(wn * 64 + j * 16 + l16) * 64 + (((h * 4 + quad) ^ rsw)) * 8]);
            #pragma unroll
            for (int i = 0; i < 4; ++i)
                #pragma unroll
                for (int j = 0; j < 4; ++j)
                    acc[i][j] = __builtin_amdgcn_mfma_f32_16x16x32_bf16(af[i], bfr[j], acc[i][j], 0, 0, 0);
        }
    }

    #pragma unroll
    for (int i = 0; i < 4; ++i) {
        #pragma unroll
        for (int j = 0; j < 4; ++j) {
            #pragma unroll
            for (int r = 0; r < 4; ++r) {
                float v = acc[i][j][r];
                int row = m0 + wm * 64 + i * 16 + quad * 4 + r;
                int col = n0 + wn * 64 + j * 16 + l16;
                if (EPI == 0) {
                    int which = col >> 10, rr = col & 1023;
                    int h = rr >> 6, d = rr & 63;
                    int b = row >> 11, sI = row & 2047;
                    size_t dst = (((size_t)(b * NH + h)) * SEQ + sI) * HDIM + d;
                    if (which == 0)      ob0[dst] = (bf16)(v * QSCALE);
                    else if (which == 1) ob1[dst] = (bf16)v;
                    else                 ob2[dst] = (bf16)v;
                } else if (EPI == 1) {
                    size_t o = (size_t)row * N + col;
                    outf[o] = resid[o] + v + bias[col];
                } else if (EPI == 2) {
                    float u = v + bias[col];
                    float y = 1.5957691216057308f * (u + 0.044715f * u * u * u);
                    float g = u * __builtin_amdgcn_rcpf(1.0f + __expf(-y));
                    ob0[(size_t)row * N + col] = (bf16)g;
                } else {   // EPI 6
                    ob0[(size_t)blockIdx.z * M * N + (size_t)row * N + col] = (bf16)v;
                }
            }
        }
    }
}

// ---------------- split-K=4 combine for W2: out = x1 + sum(p_z) + b2 --------
__global__ __launch_bounds__(256) void combine_w2(
    const bf16* __restrict__ part, const float* __restrict__ x1,
    const float* __restrict__ b2, float* __restrict__ out) {
    int i = (blockIdx.x * 256 + threadIdx.x) * 4;
    int col = i & (D_MODEL - 1);
    float4 xv = *(const float4*)(x1 + i);
    float4 bv = *(const float4*)(b2 + col);
    float4 r;
    r.x = xv.x + bv.x; r.y = xv.y + bv.y; r.z = xv.z + bv.z; r.w = xv.w + bv.w;
    #pragma unroll
    for (int z = 0; z < 4; ++z) {
        v4bf p = *(const v4bf*)(part + (size_t)z * NTOK * D_MODEL + i);
        r.x += (float)p[0]; r.y += (float)p[1]; r.z += (float)p[2]; r.w += (float)p[3];
    }
    *(float4*)(out + i) = r;
}

// ---------------- Flash attention: paired causal q-tiles, single owner ------
// Block = (bh, pair(qtA=pr, qtB=31-pr)) -> 512 blocks, each exactly 33
// key-tiles. Staged K/V tiles shared between the two q-tiles. Final O written
// directly (bf16) — no partials, no finalize.
__device__ __forceinline__ void attn_process_tile(
    int kv, int qwb, int quad, int l16,
    const bf16* Ks, const bf16* Vs, bf16* Pw,
    const v8bf& qf0, const v8bf& qf1, v4f (&o)[4], float& lsum) {
    #pragma unroll
    for (int hh = 0; hh < 2; ++hh) {
        int kb32 = kv + hh * 32;
        if (kb32 > qwb + 15) break;          // half fully above diagonal
        #pragma unroll
        for (int j2 = 0; j2 < 2; ++j2) {
            int j = hh * 2 + j2;
            int kb16 = kb32 + j2 * 16;
            union { bf16 h[4]; uint2 u; } pk;
            if (kb16 > qwb + 15) {
                pk.u = (uint2){0u, 0u};      // fully-masked sub-tile: zero-fill
            } else {
                int key = j * 16 + l16;
                v8bf ka = *(const v8bf*)(&Ks[(key * 8 + (quad ^ (key & 7))) * 8]);
                v8bf kc = *(const v8bf*)(&Ks[(key * 8 + ((quad + 4) ^ (key & 7))) * 8]);
                v4f s = (v4f){SHIFT2, SHIFT2, SHIFT2, SHIFT2};
                s = __builtin_amdgcn_mfma_f32_16x16x32_bf16(ka, qf0, s, 0, 0, 0);
                s = __builtin_amdgcn_mfma_f32_16x16x32_bf16(kc, qf1, s, 0, 0, 0);
                bool dm = (kb16 + 15 > qwb);  // straddles diagonal
                int keyb = kb16 + quad * 4;
                #pragma unroll
                for (int r = 0; r < 4; ++r) {
                    float pv = __builtin_amdgcn_exp2f(s[r]);
                    if (dm) pv = (keyb + r <= qwb + l16) ? pv : 0.f;
                    lsum += pv;
                    pk.h[r] = (bf16)pv;
                }
            }
            *(uint2*)(&Pw[l16 * 80 + j * 16 + quad * 4]) = pk.u;
        }
        v8bf pf = *(const v8bf*)(&Pw[l16 * 80 + hh * 32 + quad * 8]);
        #pragma unroll
        for (int dc = 0; dc < 4; ++dc) {
            int dim = dc * 16 + l16;
            v8bf vv = *(const v8bf*)(&Vs[(dim * 8 + ((quad + 4 * hh) ^ (dim & 7))) * 8]);
            o[dc] = __builtin_amdgcn_mfma_f32_16x16x32_bf16(pf, vv, o[dc], 0, 0, 0);
        }
    }
}

__global__ __launch_bounds__(256) void attn_kernel(
    const bf16* __restrict__ qb, const bf16* __restrict__ kb,
    const bf16* __restrict__ vt, bf16* __restrict__ ob) {
    int bh = blockIdx.x >> 4;
    int pr = blockIdx.x & 15;
    int qtA = pr, qtB = 31 - pr;

    int t = threadIdx.x;
    int wave = t >> 6, lane = t & 63;
    int quad = lane >> 4, l16 = lane & 15;
    int qwbA = qtA * 64 + wave * 16;
    int qwbB = qtB * 64 + wave * 16;

    const bf16* Qh  = qb + (size_t)bh * SEQ * HDIM;
    const bf16* Kh  = kb + (size_t)bh * SEQ * HDIM;
    const bf16* Vth = vt + (size_t)bh * HDIM * SEQ;

    __shared__ __align__(16) bf16 Ks[64 * 64];
    __shared__ __align__(16) bf16 Vs[64 * 64];
    __shared__ __align__(16) bf16 Ps[4][16 * 80];
    bf16* Pw = &Ps[wave][0];

    int u0 = t, u1 = t + 256;
    int key0 = u0 >> 3, c0 = (u0 & 7) ^ (key0 & 7);
    int key1 = u1 >> 3, c1 = (u1 & 7) ^ (key1 & 7);
    bf16* kdst0 = &Ks[wave * 512];
    bf16* kdst1 = &Ks[2048 + wave * 512];
    bf16* vdst0 = &Vs[wave * 512];
    bf16* vdst1 = &Vs[2048 + wave * 512];
    const bf16* Ksrc0 = Kh + (size_t)key0 * HDIM + c0 * 8;
    const bf16* Ksrc1 = Kh + (size_t)key1 * HDIM + c1 * 8;
    const bf16* Vsrc0 = Vth + (size_t)key0 * SEQ + c0 * 8;
    const bf16* Vsrc1 = Vth + (size_t)key1 * SEQ + c1 * 8;

    v8bf qfA0 = *(const v8bf*)(Qh + (size_t)(qwbA + l16) * HDIM + quad * 8);
    v8bf qfA1 = *(const v8bf*)(Qh + (size_t)(qwbA + l16) * HDIM + 32 + quad * 8);
    v8bf qfB0 = *(const v8bf*)(Qh + (size_t)(qwbB + l16) * HDIM + quad * 8);
    v8bf qfB1 = *(const v8bf*)(Qh + (size_t)(qwbB + l16) * HDIM + 32 + quad * 8);

    v4f oA[4], oB[4];
    #pragma unroll
    for (int dc = 0; dc < 4; ++dc) {
        oA[dc] = (v4f){0.f, 0.f, 0.f, 0.f};
        oB[dc] = (v4f){0.f, 0.f, 0.f, 0.f};
    }
    float lA = 0.f, lB = 0.f;

    int kvendA = qtA * 64 + 64;
    int kvendB = qtB * 64 + 64;
    for (int kv = 0; kv < kvendB; kv += 64) {
        __syncthreads();
        GLOAD_LDS16(Ksrc0 + (size_t)kv * HDIM, kdst0);
        GLOAD_LDS16(Ksrc1 + (size_t)kv * HDIM, kdst1);
        GLOAD_LDS16(Vsrc0 + kv, vdst0);
        GLOAD_LDS16(Vsrc1 + kv, vdst1);
        __syncthreads();
        if (kv < kvendA)
            attn_process_tile(kv, qwbA, quad, l16, Ks, Vs, Pw, qfA0, qfA1, oA, lA);
        attn_process_tile(kv, qwbB, quad, l16, Ks, Vs, Pw, qfB0, qfB1, oB, lB);
    }

    lA += __shfl_xor(lA, 16); lA += __shfl_xor(lA, 32);
    lB += __shfl_xor(lB, 16); lB += __shfl_xor(lB, 32);

    int b = bh >> 4, h = bh & 15;
    #pragma unroll
    for (int r = 0; r < 4; ++r) {
        float invA = 1.0f / __shfl(lA, quad * 4 + r);
        float invB = 1.0f / __shfl(lB, quad * 4 + r);
        int sA = qwbA + quad * 4 + r;
        int sB = qwbB + quad * 4 + r;
        #pragma unroll
        for (int dc = 0; dc < 4; ++dc) {
            int d = dc * 16 + l16;
            ob[((size_t)(b * SEQ + sA)) * D_MODEL + h * HDIM + d] = (bf16)(oA[dc][r] * invA);
            ob[((size_t)(b * SEQ + sB)) * D_MODEL + h * HDIM + d] = (bf16)(oB[dc][r] * invB);
        }
    }
}

// ---------------- launch ----------------
extern "C" void kernel_launch(void* const* d_in, const int* in_sizes, int n_in,
                              void* d_out, int out_size, void* d_ws, size_t ws_size,
                              hipStream_t stream) {
    const float* x      = (const float*)d_in[0];
    const float* scale1 = (const float*)d_in[1];
    const float* shift1 = (const float*)d_in[2];
    const float* Wqkv   = (const float*)d_in[3];
    const float* Wo_w   = (const float*)d_in[4];
    const float* Wo_b   = (const float*)d_in[5];
    const float* scale2 = (const float*)d_in[6];
    const float* shift2 = (const float*)d_in[7];
    const float* W1     = (const float*)d_in[8];
    const float* b1     = (const float*)d_in[9];
    const float* W2     = (const float*)d_in[10];
    const float* b2     = (const float*)d_in[11];
    float* out = (float*)d_out;

    char* ws = (char*)d_ws;
    size_t off = 0;
    auto alloc = [&](size_t bytes) -> char* {
        char* p = ws + off;
        off += (bytes + 255) & ~(size_t)255;
        return p;
    };
    bf16* Wqkv_b = (bf16*)alloc((size_t)3 * D_MODEL * D_MODEL * 2);
    bf16* Wo_bf  = (bf16*)alloc((size_t)D_MODEL * D_MODEL * 2);
    bf16* W1_b   = (bf16*)alloc((size_t)FF_DIM * D_MODEL * 2);
    bf16* W2_b   = (bf16*)alloc((size_t)D_MODEL * FF_DIM * 2);
    bf16* bufA   = (bf16*)alloc((size_t)NTOK * D_MODEL * 2);   // h1 / attn out / w2part[0]
    bf16* qb     = (bf16*)alloc((size_t)NTOK * D_MODEL * 2);   // q / h2 / w2part[1]
    bf16* kb     = (bf16*)alloc((size_t)NTOK * D_MODEL * 2);   // k / w2part[2]
    bf16* vb     = (bf16*)alloc((size_t)NTOK * D_MODEL * 2);   // v / w2part[3]
    bf16* vtb    = (bf16*)alloc((size_t)NTOK * D_MODEL * 2);   // V transposed
    float* x1    = (float*)alloc((size_t)NTOK * D_MODEL * 4);
    bf16* mbuf   = (bf16*)alloc((size_t)NTOK * FF_DIM * 2);
    bf16* w2part = bufA;   // 4 x 8.39 MB spans bufA..vb (all dead by W2)
    (void)ws_size; (void)n_in; (void)in_sizes; (void)out_size;

    prep_kernel<<<12288, 256, 0, stream>>>(Wqkv, Wo_w, W1, W2,
                                           Wqkv_b, Wo_bf, W1_b, W2_b);

    layernorm_kernel<<<NTOK, 256, 0, stream>>>(x, scale1, shift1, bufA);

    // merged QKV projection: N=3072
    gemm_nt<0><<<dim3(3072 / 128, NTOK / 128), 256, 0, stream>>>(
        bufA, Wqkv_b, nullptr, nullptr, nullptr, qb, kb, vb, NTOK, 3072, D_MODEL, D_MODEL);

    transpose_v<<<1024, 256, 0, stream>>>(vb, vtb);

    attn_kernel<<<512, 256, 0, stream>>>(qb, kb, vtb, bufA);

    // Wo: x1 = x + attn*Wo^T + Wo_b
    gemm_nt<1><<<dim3(D_MODEL / 128, NTOK / 128), 256, 0, stream>>>(
        bufA, Wo_bf, Wo_b, x, x1, nullptr, nullptr, nullptr, NTOK, D_MODEL, D_MODEL, D_MODEL);

    layernorm_kernel<<<NTOK, 256, 0, stream>>>(x1, scale2, shift2, qb);

    gemm_nt<2><<<dim3(FF_DIM / 128, NTOK / 128), 256, 0, stream>>>(
        qb, W1_b, b1, nullptr, nullptr, mbuf, nullptr, nullptr, NTOK, FF_DIM, D_MODEL, D_MODEL);

    // W2 split-K=4, bf16 partials, then combine
    gemm_nt<6><<<dim3(D_MODEL / 128, NTOK / 128, 4), 256, 0, stream>>>(
        mbuf, W2_b, nullptr, nullptr, nullptr, w2part, nullptr, nullptr, NTOK, D_MODEL, FF_DIM, FF_DIM / 4);

    combine_w2<<<NTOK * D_MODEL / 1024, 256, 0, stream>>>(w2part, x1, b2, out);
}

// Round 9
// 340.004 us; speedup vs baseline: 1.3283x; 1.0613x over previous
//
#include <hip/hip_runtime.h>
#include <cstdint>
#include <cstddef>

typedef __bf16 bf16;
typedef __bf16 v8bf __attribute__((ext_vector_type(8)));
typedef __bf16 v4bf __attribute__((ext_vector_type(4)));
typedef float  v4f  __attribute__((ext_vector_type(4)));

#define D_MODEL 1024
#define FF_DIM  4096
#define SEQ     2048
#define NTOK    4096   // B*S
#define NH      16
#define HDIM    64

#define GLOAD_LDS16(g, l) \
    __builtin_amdgcn_global_load_lds((const __attribute__((address_space(1))) void*)(g), \
                                     (__attribute__((address_space(3))) void*)(l), 16, 0, 0)

// q prescale: 1/8 * log2(e) so softmax uses raw exp2
#define QSCALE 0.18033688011112042f
// shift: -20 * log2(e)
#define SHIFT2 -28.853900817779268f

// ---------------- prep: all weight converts, one dispatch ------
__global__ __launch_bounds__(256) void prep_kernel(
    const float* __restrict__ Wqkv, const float* __restrict__ Wo,
    const float* __restrict__ W1, const float* __restrict__ W2,
    bf16* __restrict__ Wqkv_b, bf16* __restrict__ Wo_b,
    bf16* __restrict__ W1_b, bf16* __restrict__ W2_b) {
    int u = blockIdx.x * 256 + threadIdx.x;
    const float* src; bf16* dst; int idx;
    if (u < 786432)       { src = Wqkv; dst = Wqkv_b; idx = u * 4; }
    else if (u < 1048576) { src = Wo;   dst = Wo_b;   idx = (u - 786432) * 4; }
    else if (u < 2097152) { src = W1;   dst = W1_b;   idx = (u - 1048576) * 4; }
    else                  { src = W2;   dst = W2_b;   idx = (u - 2097152) * 4; }
    float4 v = *(const float4*)(src + idx);
    dst[idx + 0] = (bf16)v.x;
    dst[idx + 1] = (bf16)v.y;
    dst[idx + 2] = (bf16)v.z;
    dst[idx + 3] = (bf16)v.w;
}

// ---------------- LayerNorm (unbiased std, eps on std) ----------------
__global__ __launch_bounds__(256) void layernorm_kernel(
    const float* __restrict__ x, const float* __restrict__ scale,
    const float* __restrict__ shift, bf16* __restrict__ out) {
    int row = blockIdx.x;
    int t = threadIdx.x;
    const float* xr = x + (size_t)row * D_MODEL;
    float4 v = *(const float4*)(xr + t * 4);
    float s  = v.x + v.y + v.z + v.w;
    float sq = v.x * v.x + v.y * v.y + v.z * v.z + v.w * v.w;
    #pragma unroll
    for (int o = 1; o < 64; o <<= 1) {
        s  += __shfl_xor(s, o);
        sq += __shfl_xor(sq, o);
    }
    __shared__ float ws[8];
    int wv = t >> 6;
    if ((t & 63) == 0) { ws[wv * 2] = s; ws[wv * 2 + 1] = sq; }
    __syncthreads();
    s  = ws[0] + ws[2] + ws[4] + ws[6];
    sq = ws[1] + ws[3] + ws[5] + ws[7];
    float mean = s * (1.0f / D_MODEL);
    float var  = (sq - (float)D_MODEL * mean * mean) * (1.0f / (D_MODEL - 1));
    var = fmaxf(var, 0.0f);
    float inv = 1.0f / (sqrtf(var) + 1e-5f);
    #pragma unroll
    for (int j = 0; j < 4; ++j) {
        int c = t * 4 + j;
        float xv = (&v.x)[j];
        out[(size_t)row * D_MODEL + c] = (bf16)(shift[c] + scale[c] * (xv - mean) * inv);
    }
}

// ---------------- V transpose: [BH,S,HD] -> [BH,HD,S], 64x64 tiles ----------
__global__ __launch_bounds__(256) void transpose_v(
    const bf16* __restrict__ vb, bf16* __restrict__ vt) {
    int bh = blockIdx.x >> 5;
    int ts = blockIdx.x & 31;
    int t = threadIdx.x;
    __shared__ bf16 T[64][72];
    const bf16* src = vb + ((size_t)bh * SEQ + ts * 64) * HDIM;
    #pragma unroll
    for (int half = 0; half < 2; ++half) {
        int s = (t >> 3) + half * 32;
        int d0 = (t & 7) * 8;
        v8bf vv = *(const v8bf*)(src + (size_t)s * HDIM + d0);
        #pragma unroll
        for (int j = 0; j < 8; ++j) T[d0 + j][s] = vv[j];
    }
    __syncthreads();
    bf16* dst = vt + (size_t)bh * HDIM * SEQ + ts * 64;
    int d = t >> 2;
    #pragma unroll
    for (int cc = 0; cc < 2; ++cc) {
        int c = (t & 3) + cc * 4;
        v8bf o = *(const v8bf*)(&T[d][c * 8]);
        *(v8bf*)(dst + (size_t)d * SEQ + c * 8) = o;
    }
}

// ---------------- MFMA GEMM:  C[M,N] = A[M,K] * Bw[N,K]^T  ----------------
// BK=64, global_load_lds width-16 staging, XOR-swizzled LDS (chunk ^= row&7).
// Grid swizzle: groups of 16 M-tiles iterated before advancing N (L2/L3 reuse).
// EPI 0: QKV: col<1024 -> q (xQSCALE), <2048 -> k, else -> v   (all [BH,S,HD])
// EPI 1: outf = resid + C + bias          (fp32 out)
// EPI 2: ob0 = gelu(C + bias)             (bf16 out, row stride N)
// EPI 6: ob0[z*M*N + row*N + col] = C     (bf16 partial, split-K)
template <int EPI>
__global__ __launch_bounds__(256) void gemm_nt(
    const bf16* __restrict__ A, const bf16* __restrict__ Bw,
    const float* __restrict__ bias, const float* __restrict__ resid,
    float* __restrict__ outf, bf16* __restrict__ ob0,
    bf16* __restrict__ ob1, bf16* __restrict__ ob2,
    int M, int N, int K, int klen) {
    __shared__ __align__(16) bf16 As[128 * 64];
    __shared__ __align__(16) bf16 Bs[128 * 64];
    // ---- grid swizzle (gy assumed multiple of 16) ----
    int gx = gridDim.x;
    int lin = blockIdx.y * gx + blockIdx.x;
    int grpsz = 16 * gx;
    int group = lin / grpsz;
    int rem = lin - group * grpsz;
    int m_t = group * 16 + (rem & 15);
    int n_t = rem >> 4;
    int m0 = m_t * 128, n0 = n_t * 128;
    int kstart = blockIdx.z * klen;
    int t = threadIdx.x;
    int lane = t & 63, wave = t >> 6;
    int wm = wave >> 1, wn = wave & 1;
    int quad = lane >> 4, l16 = lane & 15;

    int srow8 = lane >> 3;
    int schunk = (lane & 7) ^ srow8;         // XOR swizzle
    const bf16* agp = A  + (size_t)(m0 + wave * 8 + srow8) * K + kstart + schunk * 8;
    const bf16* bgp = Bw + (size_t)(n0 + wave * 8 + srow8) * K + kstart + schunk * 8;
    size_t row32 = (size_t)32 * K;

    v4f acc[4][4];
    #pragma unroll
    for (int i = 0; i < 4; ++i)
        #pragma unroll
        for (int j = 0; j < 4; ++j)
            acc[i][j] = (v4f){0.f, 0.f, 0.f, 0.f};

    int rsw = l16 & 7;
    for (int kk = 0; kk < klen; kk += 64) {
        __syncthreads();
        #pragma unroll
        for (int ii = 0; ii < 4; ++ii) {
            GLOAD_LDS16(agp + ii * row32 + kk, &As[ii * 2048 + wave * 512]);
            GLOAD_LDS16(bgp + ii * row32 + kk, &Bs[ii * 2048 + wave * 512]);
        }
        __syncthreads();
        #pragma unroll
        for (int h = 0; h < 2; ++h) {
            v8bf af[4], bfr[4];
            #pragma unroll
            for (int i = 0; i < 4; ++i)
                af[i] = *(const v8bf*)(&As[(wm * 64 + i * 16 + l16) * 64 + (((h * 4 + quad) ^ rsw)) * 8]);
            #pragma unroll
            for (int j = 0; j < 4; ++j)
                bfr[j] = *(const v8bf*)(&Bs[(wn * 64 + j * 16 + l16) * 64 + (((h * 4 + quad) ^ rsw)) * 8]);
            #pragma unroll
            for (int i = 0; i < 4; ++i)
                #pragma unroll
                for (int j = 0; j < 4; ++j)
                    acc[i][j] = __builtin_amdgcn_mfma_f32_16x16x32_bf16(af[i], bfr[j], acc[i][j], 0, 0, 0);
        }
    }

    #pragma unroll
    for (int i = 0; i < 4; ++i) {
        #pragma unroll
        for (int j = 0; j < 4; ++j) {
            #pragma unroll
            for (int r = 0; r < 4; ++r) {
                float v = acc[i][j][r];
                int row = m0 + wm * 64 + i * 16 + quad * 4 + r;
                int col = n0 + wn * 64 + j * 16 + l16;
                if (EPI == 0) {
                    int which = col >> 10, rr = col & 1023;
                    int h = rr >> 6, d = rr & 63;
                    int b = row >> 11, sI = row & 2047;
                    size_t dst = (((size_t)(b * NH + h)) * SEQ + sI) * HDIM + d;
                    if (which == 0)      ob0[dst] = (bf16)(v * QSCALE);
                    else if (which == 1) ob1[dst] = (bf16)v;
                    else                 ob2[dst] = (bf16)v;
                } else if (EPI == 1) {
                    size_t o = (size_t)row * N + col;
                    outf[o] = resid[o] + v + bias[col];
                } else if (EPI == 2) {
                    float u = v + bias[col];
                    float y = 1.5957691216057308f * (u + 0.044715f * u * u * u);
                    float g = u * __builtin_amdgcn_rcpf(1.0f + __expf(-y));
                    ob0[(size_t)row * N + col] = (bf16)g;
                } else {   // EPI 6
                    ob0[(size_t)blockIdx.z * M * N + (size_t)row * N + col] = (bf16)v;
                }
            }
        }
    }
}

// ---------------- split-K=4 combine for W2: out = x1 + sum(p_z) + b2 --------
__global__ __launch_bounds__(256) void combine_w2(
    const bf16* __restrict__ part, const float* __restrict__ x1,
    const float* __restrict__ b2, float* __restrict__ out) {
    int i = (blockIdx.x * 256 + threadIdx.x) * 4;
    int col = i & (D_MODEL - 1);
    float4 xv = *(const float4*)(x1 + i);
    float4 bv = *(const float4*)(b2 + col);
    float4 r;
    r.x = xv.x + bv.x; r.y = xv.y + bv.y; r.z = xv.z + bv.z; r.w = xv.w + bv.w;
    #pragma unroll
    for (int z = 0; z < 4; ++z) {
        v4bf p = *(const v4bf*)(part + (size_t)z * NTOK * D_MODEL + i);
        r.x += (float)p[0]; r.y += (float)p[1]; r.z += (float)p[2]; r.w += (float)p[3];
    }
    *(float4*)(out + i) = r;
}

// ---------------- Flash attention: paired causal q-tiles, single owner ------
// Block index: bh fastest (bh = blockIdx.x & 31) so all 16 pair-blocks of a
// head land on the same XCD (stride 32 ≡ 0 mod 8) -> K/V^T stay L2-resident.
__device__ __forceinline__ void attn_process_tile(
    int kv, int qwb, int quad, int l16,
    const bf16* Ks, const bf16* Vs, bf16* Pw,
    const v8bf& qf0, const v8bf& qf1, v4f (&o)[4], float& lsum) {
    #pragma unroll
    for (int hh = 0; hh < 2; ++hh) {
        int kb32 = kv + hh * 32;
        if (kb32 > qwb + 15) break;          // half fully above diagonal
        #pragma unroll
        for (int j2 = 0; j2 < 2; ++j2) {
            int j = hh * 2 + j2;
            int kb16 = kb32 + j2 * 16;
            union { bf16 h[4]; uint2 u; } pk;
            if (kb16 > qwb + 15) {
                pk.u = (uint2){0u, 0u};      // fully-masked sub-tile: zero-fill
            } else {
                int key = j * 16 + l16;
                v8bf ka = *(const v8bf*)(&Ks[(key * 8 + (quad ^ (key & 7))) * 8]);
                v8bf kc = *(const v8bf*)(&Ks[(key * 8 + ((quad + 4) ^ (key & 7))) * 8]);
                v4f s = (v4f){SHIFT2, SHIFT2, SHIFT2, SHIFT2};
                s = __builtin_amdgcn_mfma_f32_16x16x32_bf16(ka, qf0, s, 0, 0, 0);
                s = __builtin_amdgcn_mfma_f32_16x16x32_bf16(kc, qf1, s, 0, 0, 0);
                bool dm = (kb16 + 15 > qwb);  // straddles diagonal
                int keyb = kb16 + quad * 4;
                #pragma unroll
                for (int r = 0; r < 4; ++r) {
                    float pv = __builtin_amdgcn_exp2f(s[r]);
                    if (dm) pv = (keyb + r <= qwb + l16) ? pv : 0.f;
                    lsum += pv;
                    pk.h[r] = (bf16)pv;
                }
            }
            *(uint2*)(&Pw[l16 * 80 + j * 16 + quad * 4]) = pk.u;
        }
        v8bf pf = *(const v8bf*)(&Pw[l16 * 80 + hh * 32 + quad * 8]);
        #pragma unroll
        for (int dc = 0; dc < 4; ++dc) {
            int dim = dc * 16 + l16;
            v8bf vv = *(const v8bf*)(&Vs[(dim * 8 + ((quad + 4 * hh) ^ (dim & 7))) * 8]);
            o[dc] = __builtin_amdgcn_mfma_f32_16x16x32_bf16(pf, vv, o[dc], 0, 0, 0);
        }
    }
}

__global__ __launch_bounds__(256) void attn_kernel(
    const bf16* __restrict__ qb, const bf16* __restrict__ kb,
    const bf16* __restrict__ vt, bf16* __restrict__ ob) {
    int bh = blockIdx.x & 31;          // bh fastest -> same-XCD per head
    int pr = blockIdx.x >> 5;
    int qtA = pr, qtB = 31 - pr;

    int t = threadIdx.x;
    int wave = t >> 6, lane = t & 63;
    int quad = lane >> 4, l16 = lane & 15;
    int qwbA = qtA * 64 + wave * 16;
    int qwbB = qtB * 64 + wave * 16;

    const bf16* Qh  = qb + (size_t)bh * SEQ * HDIM;
    const bf16* Kh  = kb + (size_t)bh * SEQ * HDIM;
    const bf16* Vth = vt + (size_t)bh * HDIM * SEQ;

    __shared__ __align__(16) bf16 Ks[64 * 64];
    __shared__ __align__(16) bf16 Vs[64 * 64];
    __shared__ __align__(16) bf16 Ps[4][16 * 80];
    bf16* Pw = &Ps[wave][0];

    int u0 = t, u1 = t + 256;
    int key0 = u0 >> 3, c0 = (u0 & 7) ^ (key0 & 7);
    int key1 = u1 >> 3, c1 = (u1 & 7) ^ (key1 & 7);
    bf16* kdst0 = &Ks[wave * 512];
    bf16* kdst1 = &Ks[2048 + wave * 512];
    bf16* vdst0 = &Vs[wave * 512];
    bf16* vdst1 = &Vs[2048 + wave * 512];
    const bf16* Ksrc0 = Kh + (size_t)key0 * HDIM + c0 * 8;
    const bf16* Ksrc1 = Kh + (size_t)key1 * HDIM + c1 * 8;
    const bf16* Vsrc0 = Vth + (size_t)key0 * SEQ + c0 * 8;
    const bf16* Vsrc1 = Vth + (size_t)key1 * SEQ + c1 * 8;

    v8bf qfA0 = *(const v8bf*)(Qh + (size_t)(qwbA + l16) * HDIM + quad * 8);
    v8bf qfA1 = *(const v8bf*)(Qh + (size_t)(qwbA + l16) * HDIM + 32 + quad * 8);
    v8bf qfB0 = *(const v8bf*)(Qh + (size_t)(qwbB + l16) * HDIM + quad * 8);
    v8bf qfB1 = *(const v8bf*)(Qh + (size_t)(qwbB + l16) * HDIM + 32 + quad * 8);

    v4f oA[4], oB[4];
    #pragma unroll
    for (int dc = 0; dc < 4; ++dc) {
        oA[dc] = (v4f){0.f, 0.f, 0.f, 0.f};
        oB[dc] = (v4f){0.f, 0.f, 0.f, 0.f};
    }
    float lA = 0.f, lB = 0.f;

    int kvendA = qtA * 64 + 64;
    int kvendB = qtB * 64 + 64;
    for (int kv = 0; kv < kvendB; kv += 64) {
        __syncthreads();
        GLOAD_LDS16(Ksrc0 + (size_t)kv * HDIM, kdst0);
        GLOAD_LDS16(Ksrc1 + (size_t)kv * HDIM, kdst1);
        GLOAD_LDS16(Vsrc0 + kv, vdst0);
        GLOAD_LDS16(Vsrc1 + kv, vdst1);
        __syncthreads();
        if (kv < kvendA)
            attn_process_tile(kv, qwbA, quad, l16, Ks, Vs, Pw, qfA0, qfA1, oA, lA);
        attn_process_tile(kv, qwbB, quad, l16, Ks, Vs, Pw, qfB0, qfB1, oB, lB);
    }

    lA += __shfl_xor(lA, 16); lA += __shfl_xor(lA, 32);
    lB += __shfl_xor(lB, 16); lB += __shfl_xor(lB, 32);

    int b = bh >> 4, h = bh & 15;
    #pragma unroll
    for (int r = 0; r < 4; ++r) {
        float invA = 1.0f / __shfl(lA, quad * 4 + r);
        float invB = 1.0f / __shfl(lB, quad * 4 + r);
        int sA = qwbA + quad * 4 + r;
        int sB = qwbB + quad * 4 + r;
        #pragma unroll
        for (int dc = 0; dc < 4; ++dc) {
            int d = dc * 16 + l16;
            ob[((size_t)(b * SEQ + sA)) * D_MODEL + h * HDIM + d] = (bf16)(oA[dc][r] * invA);
            ob[((size_t)(b * SEQ + sB)) * D_MODEL + h * HDIM + d] = (bf16)(oB[dc][r] * invB);
        }
    }
}

// ---------------- launch ----------------
extern "C" void kernel_launch(void* const* d_in, const int* in_sizes, int n_in,
                              void* d_out, int out_size, void* d_ws, size_t ws_size,
                              hipStream_t stream) {
    const float* x      = (const float*)d_in[0];
    const float* scale1 = (const float*)d_in[1];
    const float* shift1 = (const float*)d_in[2];
    const float* Wqkv   = (const float*)d_in[3];
    const float* Wo_w   = (const float*)d_in[4];
    const float* Wo_b   = (const float*)d_in[5];
    const float* scale2 = (const float*)d_in[6];
    const float* shift2 = (const float*)d_in[7];
    const float* W1     = (const float*)d_in[8];
    const float* b1     = (const float*)d_in[9];
    const float* W2     = (const float*)d_in[10];
    const float* b2     = (const float*)d_in[11];
    float* out = (float*)d_out;

    char* ws = (char*)d_ws;
    size_t off = 0;
    auto alloc = [&](size_t bytes) -> char* {
        char* p = ws + off;
        off += (bytes + 255) & ~(size_t)255;
        return p;
    };
    bf16* Wqkv_b = (bf16*)alloc((size_t)3 * D_MODEL * D_MODEL * 2);
    bf16* Wo_bf  = (bf16*)alloc((size_t)D_MODEL * D_MODEL * 2);
    bf16* W1_b   = (bf16*)alloc((size_t)FF_DIM * D_MODEL * 2);
    bf16* W2_b   = (bf16*)alloc((size_t)D_MODEL * FF_DIM * 2);
    bf16* bufA   = (bf16*)alloc((size_t)NTOK * D_MODEL * 2);   // h1 / attn out / w2part[0]
    bf16* qb     = (bf16*)alloc((size_t)NTOK * D_MODEL * 2);   // q / h2 / w2part[1]
    bf16* kb     = (bf16*)alloc((size_t)NTOK * D_MODEL * 2);   // k / w2part[2]
    bf16* vb     = (bf16*)alloc((size_t)NTOK * D_MODEL * 2);   // v / w2part[3]
    bf16* vtb    = (bf16*)alloc((size_t)NTOK * D_MODEL * 2);   // V transposed
    float* x1    = (float*)alloc((size_t)NTOK * D_MODEL * 4);
    bf16* mbuf   = (bf16*)alloc((size_t)NTOK * FF_DIM * 2);
    bf16* w2part = bufA;   // 4 x 8.39 MB spans bufA..vb (all dead by W2)
    (void)ws_size; (void)n_in; (void)in_sizes; (void)out_size;

    prep_kernel<<<12288, 256, 0, stream>>>(Wqkv, Wo_w, W1, W2,
                                           Wqkv_b, Wo_bf, W1_b, W2_b);

    layernorm_kernel<<<NTOK, 256, 0, stream>>>(x, scale1, shift1, bufA);

    // merged QKV projection: N=3072
    gemm_nt<0><<<dim3(3072 / 128, NTOK / 128), 256, 0, stream>>>(
        bufA, Wqkv_b, nullptr, nullptr, nullptr, qb, kb, vb, NTOK, 3072, D_MODEL, D_MODEL);

    transpose_v<<<1024, 256, 0, stream>>>(vb, vtb);

    attn_kernel<<<512, 256, 0, stream>>>(qb, kb, vtb, bufA);

    // Wo: x1 = x + attn*Wo^T + Wo_b
    gemm_nt<1><<<dim3(D_MODEL / 128, NTOK / 128), 256, 0, stream>>>(
        bufA, Wo_bf, Wo_b, x, x1, nullptr, nullptr, nullptr, NTOK, D_MODEL, D_MODEL, D_MODEL);

    layernorm_kernel<<<NTOK, 256, 0, stream>>>(x1, scale2, shift2, qb);

    gemm_nt<2><<<dim3(FF_DIM / 128, NTOK / 128), 256, 0, stream>>>(
        qb, W1_b, b1, nullptr, nullptr, mbuf, nullptr, nullptr, NTOK, FF_DIM, D_MODEL, D_MODEL);

    // W2 split-K=4, bf16 partials, then combine
    gemm_nt<6><<<dim3(D_MODEL / 128, NTOK / 128, 4), 256, 0, stream>>>(
        mbuf, W2_b, nullptr, nullptr, nullptr, w2part, nullptr, nullptr, NTOK, D_MODEL, FF_DIM, FF_DIM / 4);

    combine_w2<<<NTOK * D_MODEL / 1024, 256, 0, stream>>>(w2part, x1, b2, out);
}